// Round 10
// baseline (412.678 us; speedup 1.0000x reference)
//
#include <hip/hip_runtime.h>
#include <math.h>

#define EPS 1e-6f

namespace {

typedef unsigned short u16;
typedef unsigned int u32;
typedef __bf16 bf16x8 __attribute__((ext_vector_type(8)));
typedef float f32x4 __attribute__((ext_vector_type(4)));
typedef u16 u16x8 __attribute__((ext_vector_type(8)));

constexpr int Bb = 4, Ss = 512, Dd = 512, Ii = 1024, Cc = 64;
constexpr int nCk = 8, RowsC = 256, RowsAll = 2048;

__device__ __forceinline__ float sigmoidf_(float x) { return 1.f / (1.f + expf(-x)); }
__device__ __forceinline__ float siluf_(float x)    { return x / (1.f + expf(-x)); }

__device__ __forceinline__ u16 f2bf(float f) {
  u32 u = __float_as_uint(f);
  u32 r = u + 0x7fffu + ((u >> 16) & 1u);
  return (u16)(r >> 16);
}
__device__ __forceinline__ float bf2f(u16 u) {
  return __uint_as_float(((u32)u) << 16);
}

__device__ __forceinline__ void llds16(const u16* g, u16* l) {
  __builtin_amdgcn_global_load_lds((__attribute__((address_space(1))) void*)g,
                                   (__attribute__((address_space(3))) void*)l,
                                   16, 0, 0);
}

__device__ __forceinline__ void drain_barrier() {
  asm volatile("s_waitcnt vmcnt(0)" ::: "memory");
  __builtin_amdgcn_s_barrier();
}

__device__ __forceinline__ float wave_sum(float v) {
  #pragma unroll
  for (int m = 32; m > 0; m >>= 1) v += __shfl_xor(v, m, 64);
  return v;
}

__device__ __forceinline__ float block_reduce_sum(float v, float* red) {
  int tid = threadIdx.x;
  red[tid] = v; __syncthreads();
  for (int s = 128; s > 0; s >>= 1) {
    if (tid < s) red[tid] += red[tid + s];
    __syncthreads();
  }
  float r = red[0]; __syncthreads();
  return r;
}

// ---------------- workspace carve ----------------
struct WS {
  float *w0c, *Sw0, *w1c, *Sw1, *lnc, *Sln, *Krows, *Vrows,
        *Yp, *gyr, *alv, *thv, *etv, *wBv, *wEv, *scal, *Qb;
  u16 *xcb, *wkvqb, *w0b, *w1b, *w1tb, *Kb, *KT, *Ht, *dZb,
      *dYb, *dYtW, *dYtE, *dHtW, *dHtE, *Qbb, *Hrb;
};
__host__ __device__ inline WS mkws(char* base) {
  WS s; char* p = base + 256;
#define CF(nm, n) s.nm = (float*)p; p += (size_t)(n) * 4;
#define CU(nm, n) s.nm = (u16*)p;   p += (size_t)(n) * 2;
  CF(w0c, Ii*Dd) CF(Sw0, Ii*Dd) CF(w1c, Dd*Ii) CF(Sw1, Dd*Ii)
  CF(lnc, Dd) CF(Sln, Dd)
  CF(Krows, (size_t)RowsAll*Dd) CF(Vrows, (size_t)RowsAll*Dd)
  CF(Yp, (size_t)16*RowsC*Dd) CF(gyr, RowsC*Dd)
  CF(alv, Ss) CF(thv, Ss) CF(etv, Ss) CF(wBv, nCk*RowsC) CF(wEv, nCk*RowsC) CF(scal, nCk*4)
  CF(Qb, (size_t)RowsAll*Dd)
  CU(xcb, (size_t)RowsAll*Dd) CU(wkvqb, (size_t)3*Dd*Dd)
  CU(w0b, (size_t)Ii*Dd) CU(w1b, (size_t)2*Dd*Ii) CU(w1tb, (size_t)2*Ii*Dd)
  CU(Kb, (size_t)RowsAll*Dd) CU(KT, (size_t)RowsAll*Dd)
  CU(Ht, RowsC*Ii) CU(dZb, RowsC*Ii)
  CU(dYb, RowsC*Dd) CU(dYtW, RowsC*Dd) CU(dYtE, RowsC*Dd)
  CU(dHtW, RowsC*Ii) CU(dHtE, RowsC*Ii)
  CU(Qbb, (size_t)RowsAll*Dd) CU(Hrb, (size_t)RowsAll*Ii)
#undef CF
#undef CU
  return s;
}

// ---------------- 64x64 MFMA tile, BK/NBUF-param ----------------
// EPI: 0 C0=v | 3 dh=v*bf2f(Zb): CbT=bf(dh*wB)^T, CbT2=bf(dh*wE)^T
//      5 C0=silu(v)
template<int BK, int NBUF, int EPI>
__device__ void tile64(
    u16* smA, u16* smB,
    const u16* __restrict__ A, const u16* __restrict__ Bt,
    int K, int N, int bm, int bn,
    float* C0, u16* CbT, u16* CbT2,
    const u16* Zb, const float* wB, const float* wE, int trM)
{
  constexpr int CPR = BK / 8;
  constexpr int NISS = (64 * CPR) / 256;
  constexpr int BUF = 64 * BK;
  const int tid = threadIdx.x;
  const int l = tid & 63, lr = l & 15, lq = l >> 4;
  const int w = tid >> 6, wr = w >> 1, wc = w & 1;

  f32x4 acc[2][2];
  #pragma unroll
  for (int i = 0; i < 2; ++i)
    #pragma unroll
    for (int j = 0; j < 2; ++j) acc[i][j] = f32x4{0.f, 0.f, 0.f, 0.f};

  auto stage = [&](int k0, int buf) {
    u16* dA = smA + buf * BUF;
    u16* dB = smB + buf * BUF;
    #pragma unroll
    for (int i = 0; i < NISS; ++i) {
      int e = i * 256 + tid;
      int r = e / CPR, c = (e & (CPR - 1)) ^ (r & (CPR - 1));
      llds16(A  + (size_t)(bm + r) * K + k0 + c * 8, dA + e * 8);
      llds16(Bt + (size_t)(bn + r) * K + k0 + c * 8, dB + e * 8);
    }
  };

  stage(0, 0);
  drain_barrier();
  const int nt = K / BK;
  int cur = 0;
  for (int t = 0; t < nt; ++t) {
    if (t + 1 < nt) stage((t + 1) * BK, (cur ^ 1) & (NBUF - 1));
    const u16* sA = smA + cur * BUF;
    const u16* sB = smB + cur * BUF;
    #pragma unroll
    for (int kk = 0; kk < BK / 32; ++kk) {
      bf16x8 av[2], bv[2];
      #pragma unroll
      for (int m = 0; m < 2; ++m) {
        int r = wr * 32 + m * 16 + lr;
        int c = (kk * 4 + lq) ^ (r & (CPR - 1));
        av[m] = *reinterpret_cast<const bf16x8*>(&sA[r * BK + c * 8]);
      }
      #pragma unroll
      for (int n = 0; n < 2; ++n) {
        int r = wc * 32 + n * 16 + lr;
        int c = (kk * 4 + lq) ^ (r & (CPR - 1));
        bv[n] = *reinterpret_cast<const bf16x8*>(&sB[r * BK + c * 8]);
      }
      #pragma unroll
      for (int m = 0; m < 2; ++m)
        #pragma unroll
        for (int n = 0; n < 2; ++n)
          acc[m][n] = __builtin_amdgcn_mfma_f32_16x16x32_bf16(av[m], bv[n], acc[m][n], 0, 0, 0);
    }
    drain_barrier();
    cur = (cur ^ 1) & (NBUF - 1);
  }

  #pragma unroll
  for (int m = 0; m < 2; ++m) {
    int gr0 = bm + wr * 32 + m * 16 + lq * 4;
    float wbq[4], weq[4];
    if (EPI == 3) {
      #pragma unroll
      for (int q = 0; q < 4; ++q) { wbq[q] = wB[gr0 + q]; weq[q] = wE[gr0 + q]; }
    }
    #pragma unroll
    for (int n = 0; n < 2; ++n) {
      int gc = bn + wc * 32 + n * 16 + lr;
      ushort4 t1, t2;
      #pragma unroll
      for (int q = 0; q < 4; ++q) {
        float v = acc[m][n][q];
        size_t idx = (size_t)(gr0 + q) * N + gc;
        if (EPI == 0) {
          C0[idx] = v;
        } else if (EPI == 3) {
          float dh = v * bf2f(Zb[idx]);
          ((u16*)&t1)[q] = f2bf(dh * wbq[q]);
          ((u16*)&t2)[q] = f2bf(dh * weq[q]);
        } else if (EPI == 5) {
          C0[idx] = siluf_(v);
        }
      }
      if (EPI == 3) {
        *reinterpret_cast<ushort4*>(&CbT[(size_t)gc * trM + gr0]) = t1;
        *reinterpret_cast<ushort4*>(&CbT2[(size_t)gc * trM + gr0]) = t2;
      }
    }
  }
}

// ------------- dual-weighted grad tile + fused param update -----------
template<int BK, int NBUF, bool TR>
__device__ void gtile64(
    u16* smA, u16* smB, u16* smE,
    const u16* __restrict__ AW, const u16* __restrict__ AE,
    const u16* __restrict__ Bt,
    float* P, float* Sm, u16* Pb, u16* PbT, const float* scal,
    int M, int N, int K, int bm, int bn)
{
  constexpr int CPR = BK / 8;
  constexpr int NISS = (64 * CPR) / 256;
  constexpr int BUF = 64 * BK;
  const int tid = threadIdx.x;
  const int l = tid & 63, lr = l & 15, lq = l >> 4;
  const int w = tid >> 6, wr = w >> 1, wc = w & 1;

  f32x4 aM[2][2], aE[2][2];
  #pragma unroll
  for (int i = 0; i < 2; ++i)
    #pragma unroll
    for (int j = 0; j < 2; ++j) {
      aM[i][j] = f32x4{0.f, 0.f, 0.f, 0.f};
      aE[i][j] = f32x4{0.f, 0.f, 0.f, 0.f};
    }

  auto stage = [&](int k0, int buf) {
    u16* dA = smA + buf * BUF;
    u16* dE = smE + buf * BUF;
    u16* dB = smB + buf * BUF;
    #pragma unroll
    for (int i = 0; i < NISS; ++i) {
      int e = i * 256 + tid;
      int r = e / CPR, c = (e & (CPR - 1)) ^ (r & (CPR - 1));
      llds16(AW + (size_t)(bm + r) * K + k0 + c * 8, dA + e * 8);
      llds16(AE + (size_t)(bm + r) * K + k0 + c * 8, dE + e * 8);
      llds16(Bt + (size_t)(bn + r) * K + k0 + c * 8, dB + e * 8);
    }
  };

  stage(0, 0);
  drain_barrier();
  const int nt = K / BK;
  int cur = 0;
  for (int t = 0; t < nt; ++t) {
    if (t + 1 < nt) stage((t + 1) * BK, (cur ^ 1) & (NBUF - 1));
    const u16* sA = smA + cur * BUF;
    const u16* sE = smE + cur * BUF;
    const u16* sB = smB + cur * BUF;
    #pragma unroll
    for (int kk = 0; kk < BK / 32; ++kk) {
      bf16x8 awv[2], aev[2], bv[2];
      #pragma unroll
      for (int m = 0; m < 2; ++m) {
        int r = wr * 32 + m * 16 + lr;
        int c = (kk * 4 + lq) ^ (r & (CPR - 1));
        awv[m] = *reinterpret_cast<const bf16x8*>(&sA[r * BK + c * 8]);
        aev[m] = *reinterpret_cast<const bf16x8*>(&sE[r * BK + c * 8]);
      }
      #pragma unroll
      for (int n = 0; n < 2; ++n) {
        int r = wc * 32 + n * 16 + lr;
        int c = (kk * 4 + lq) ^ (r & (CPR - 1));
        bv[n] = *reinterpret_cast<const bf16x8*>(&sB[r * BK + c * 8]);
      }
      #pragma unroll
      for (int m = 0; m < 2; ++m)
        #pragma unroll
        for (int n = 0; n < 2; ++n) {
          aM[m][n] = __builtin_amdgcn_mfma_f32_16x16x32_bf16(awv[m], bv[n], aM[m][n], 0, 0, 0);
          aE[m][n] = __builtin_amdgcn_mfma_f32_16x16x32_bf16(aev[m], bv[n], aE[m][n], 0, 0, 0);
        }
    }
    drain_barrier();
    cur = (cur ^ 1) & (NBUF - 1);
  }

  float s0 = scal[0], s1 = scal[1], s2 = scal[2];
  #pragma unroll
  for (int m = 0; m < 2; ++m) {
    int gr0 = bm + wr * 32 + m * 16 + lq * 4;
    #pragma unroll
    for (int n = 0; n < 2; ++n) {
      int gc = bn + wc * 32 + n * 16 + lr;
      ushort4 t1;
      #pragma unroll
      for (int q = 0; q < 4; ++q) {
        size_t idx = (size_t)(gr0 + q) * N + gc;
        float p = P[idx], s = Sm[idx];
        float np = s0 * p + s1 * s - aM[m][n][q];
        float ns = s2 * s - aE[m][n][q];
        P[idx] = np; Sm[idx] = ns;
        Pb[idx] = f2bf(np);
        if (TR) ((u16*)&t1)[q] = f2bf(np);
      }
      if (TR) *reinterpret_cast<ushort4*>(&PbT[(size_t)gc * M + gr0]) = t1;
    }
  }
}

// ---------------- row-complete 64-row x 512-col GEMM ----------------
// C[64][512] = A[bm..bm+64][KTOT] @ Bt[512][KTOT]^T, BK=32 dbuf.
// EPI 0: K-norm -> Krows f32, Kb bf16, KT transposed bf16 (per chunk)
// EPI 1: Q-norm -> Qb f32, Qbb bf16
// EPI 2: retrieval final -> out = Qb + rms(y)*lnc (permuted rows)
template<int KTOT, int EPI>
__device__ void rowgemm(u16* sm,
    const u16* __restrict__ A, const u16* __restrict__ Bt, int bm,
    float* C0f, u16* C0b, u16* KT, const float* nw,
    const float* Qb2, float* out)
{
  constexpr int BK = 32, CPR = 4;
  constexpr int ABUF = 64 * BK, BBUF = 512 * BK;
  u16* smA = sm;              // 2 * 2048
  u16* smB = sm + 2 * ABUF;   // 2 * 16384
  const int tid = threadIdx.x;
  const int l = tid & 63, lr = l & 15, lq = l >> 4;
  const int w = tid >> 6;

  f32x4 acc[32];
  #pragma unroll
  for (int n = 0; n < 32; ++n) acc[n] = f32x4{0.f, 0.f, 0.f, 0.f};

  auto stage = [&](int k0, int buf) {
    {
      int e = tid;
      int r = e >> 2, c = (e & 3) ^ (r & 3);
      llds16(A + (size_t)(bm + r) * KTOT + k0 + c * 8, smA + buf * ABUF + e * 8);
    }
    #pragma unroll
    for (int i = 0; i < 8; ++i) {
      int e = i * 256 + tid;
      int r = e >> 2, c = (e & 3) ^ (r & 3);
      llds16(Bt + (size_t)r * KTOT + k0 + c * 8, smB + buf * BBUF + e * 8);
    }
  };

  stage(0, 0);
  drain_barrier();
  const int nt = KTOT / BK;
  int cur = 0;
  for (int t = 0; t < nt; ++t) {
    if (t + 1 < nt) stage((t + 1) * BK, cur ^ 1);
    const u16* sA = smA + cur * ABUF;
    const u16* sB = smB + cur * BBUF;
    int ra = w * 16 + lr;
    int ca = lq ^ (ra & 3);
    bf16x8 av = *reinterpret_cast<const bf16x8*>(&sA[ra * BK + ca * 8]);
    #pragma unroll
    for (int n = 0; n < 32; ++n) {
      int rb = n * 16 + lr;
      int cb = lq ^ (rb & 3);
      bf16x8 bv = *reinterpret_cast<const bf16x8*>(&sB[rb * BK + cb * 8]);
      acc[n] = __builtin_amdgcn_mfma_f32_16x16x32_bf16(av, bv, acc[n], 0, 0, 0);
    }
    drain_barrier();
    cur ^= 1;
  }

  // rows: bm + w*16 + lq*4 + q ; cols: n*16 + lr
  if (EPI == 0 || EPI == 1) {
    // silu in place + row sum-of-squares
    float ssq[4] = {0.f, 0.f, 0.f, 0.f};
    #pragma unroll
    for (int n = 0; n < 32; ++n)
      #pragma unroll
      for (int q = 0; q < 4; ++q) {
        float s = siluf_(acc[n][q]);
        acc[n][q] = s;
        ssq[q] += s * s;
      }
    #pragma unroll
    for (int q = 0; q < 4; ++q) {
      #pragma unroll
      for (int msk = 1; msk < 16; msk <<= 1) ssq[q] += __shfl_xor(ssq[q], msk, 64);
      ssq[q] = rsqrtf(ssq[q] / (float)Dd + EPS);
    }
    const int rl0 = w * 16 + lq * 4;
    u16* lt = sm;                          // 64 x pitch-516 u16 repack area
    #pragma unroll
    for (int n = 0; n < 32; ++n) {
      int col = n * 16 + lr;
      float nv = nw[col];
      #pragma unroll
      for (int q = 0; q < 4; ++q) {
        float y = acc[n][q] * ssq[q] * nv;
        u16 yb = f2bf(y);
        size_t idx = (size_t)(bm + rl0 + q) * Dd + col;
        C0f[idx] = y;
        C0b[idx] = yb;
        if (EPI == 0) lt[(rl0 + q) * 516 + col] = yb;
      }
    }
    if (EPI == 0) {
      __syncthreads();
      int ci = bm >> 8, rloc = bm & 255;
      u16* KTc = KT + (size_t)ci * Dd * RowsC;
      #pragma unroll
      for (int i = 0; i < 16; ++i) {
        int task = i * 256 + tid;            // 4096 tasks
        int col = task >> 3, g = task & 7;
        u16x8 pk;
        #pragma unroll
        for (int j = 0; j < 8; ++j) pk[j] = lt[(g * 8 + j) * 516 + col];
        *reinterpret_cast<u16x8*>(&KTc[(size_t)col * RowsC + rloc + g * 8]) = pk;
      }
    }
  } else {
    // EPI 2: y = acc (no silu); out = Qb + rms(y)*lnc, permuted rows
    float ssq[4] = {0.f, 0.f, 0.f, 0.f};
    #pragma unroll
    for (int n = 0; n < 32; ++n)
      #pragma unroll
      for (int q = 0; q < 4; ++q) ssq[q] += acc[n][q] * acc[n][q];
    #pragma unroll
    for (int q = 0; q < 4; ++q) {
      #pragma unroll
      for (int msk = 1; msk < 16; msk <<= 1) ssq[q] += __shfl_xor(ssq[q], msk, 64);
      ssq[q] = rsqrtf(ssq[q] / (float)Dd + EPS);
    }
    const int rl0 = w * 16 + lq * 4;
    #pragma unroll
    for (int q = 0; q < 4; ++q) {
      int row = bm + rl0 + q;
      int ci = row >> 8, wi = row & 255, b = wi >> 6, t = wi & 63;
      float* ob = out + ((size_t)b * Ss + ci * Cc + t) * Dd;
      const float* qb = Qb2 + (size_t)row * Dd;
      #pragma unroll
      for (int n = 0; n < 32; ++n) {
        int col = n * 16 + lr;
        ob[col] = qb[col] + acc[n][q] * ssq[q] * nw[col];
      }
    }
  }
}

// ---------------- kernels ----------------

// Fused Z0 + split-K partial Y (unchanged from R9)
__global__ __launch_bounds__(256) void z0y_k(
    const u16* __restrict__ Kbc, const u16* __restrict__ w0b,
    const u16* __restrict__ w1b,
    u16* __restrict__ Ht, u16* __restrict__ dZb, float* __restrict__ Yp)
{
  __shared__ __align__(16) u16 sm[4 * 64 * 128 + 64 * 64];  // 72 KB
  u16* Hs = sm + 4 * 64 * 128;
  const int tid = threadIdx.x;
  const int l = tid & 63, lr = l & 15, lq = l >> 4;
  const int w = tid >> 6, wr = w >> 1, wc = w & 1;
  const int tj = blockIdx.x, tr = blockIdx.y;
  const int bm = tr * 64, bn = tj * 64;

  {
    constexpr int BK = 128, CPR = 16, NISS = 4, BUF = 64 * BK;
    u16* smA = sm; u16* smB = sm + 2 * BUF;
    f32x4 acc[2][2];
    #pragma unroll
    for (int i = 0; i < 2; ++i)
      #pragma unroll
      for (int j = 0; j < 2; ++j) acc[i][j] = f32x4{0.f, 0.f, 0.f, 0.f};

    auto stage = [&](int k0, int buf) {
      u16* dA = smA + buf * BUF;
      u16* dB = smB + buf * BUF;
      #pragma unroll
      for (int i = 0; i < NISS; ++i) {
        int e = i * 256 + tid;
        int r = e / CPR, c = (e & (CPR - 1)) ^ (r & (CPR - 1));
        llds16(Kbc + (size_t)(bm + r) * Dd + k0 + c * 8, dA + e * 8);
        llds16(w0b + (size_t)(bn + r) * Dd + k0 + c * 8, dB + e * 8);
      }
    };
    stage(0, 0);
    drain_barrier();
    int cur = 0;
    for (int t = 0; t < 4; ++t) {
      if (t + 1 < 4) stage((t + 1) * BK, cur ^ 1);
      const u16* sA = smA + cur * BUF;
      const u16* sB = smB + cur * BUF;
      #pragma unroll
      for (int kk = 0; kk < 4; ++kk) {
        bf16x8 av[2], bv[2];
        #pragma unroll
        for (int m = 0; m < 2; ++m) {
          int r = wr * 32 + m * 16 + lr;
          int c = (kk * 4 + lq) ^ (r & (CPR - 1));
          av[m] = *reinterpret_cast<const bf16x8*>(&sA[r * BK + c * 8]);
        }
        #pragma unroll
        for (int n = 0; n < 2; ++n) {
          int r = wc * 32 + n * 16 + lr;
          int c = (kk * 4 + lq) ^ (r & (CPR - 1));
          bv[n] = *reinterpret_cast<const bf16x8*>(&sB[r * BK + c * 8]);
        }
        #pragma unroll
        for (int m = 0; m < 2; ++m)
          #pragma unroll
          for (int n = 0; n < 2; ++n)
            acc[m][n] = __builtin_amdgcn_mfma_f32_16x16x32_bf16(av[m], bv[n], acc[m][n], 0, 0, 0);
      }
      drain_barrier();
      cur ^= 1;
    }

    #pragma unroll
    for (int i = 0; i < 16; ++i) {
      int e = i * 256 + tid;
      int r = e >> 3, c = (e & 7) ^ (r & 7);
      llds16(w1b + (size_t)r * Ii + bn + c * 8, sm + e * 8);
    }

    #pragma unroll
    for (int m = 0; m < 2; ++m) {
      int gr0 = bm + wr * 32 + m * 16 + lq * 4;
      int rl0 = wr * 32 + m * 16 + lq * 4;
      #pragma unroll
      for (int n = 0; n < 2; ++n) {
        int gc = bn + wc * 32 + n * 16 + lr;
        int cl = wc * 32 + n * 16 + lr;
        ushort4 t1;
        #pragma unroll
        for (int q = 0; q < 4; ++q) {
          float v = acc[m][n][q];
          float sg = 1.f / (1.f + expf(-v));
          float h = v * sg;
          float ds = sg * (1.f + v * (1.f - sg));
          u16 hb = f2bf(h);
          ((u16*)&t1)[q] = hb;
          dZb[(size_t)(gr0 + q) * Ii + gc] = f2bf(ds);
          int rl = rl0 + q;
          Hs[rl * 64 + ((((cl >> 3) ^ (rl & 7)) << 3) | (cl & 7))] = hb;
        }
        *reinterpret_cast<ushort4*>(&Ht[(size_t)gc * RowsC + gr0]) = t1;
      }
    }
  }

  asm volatile("s_waitcnt vmcnt(0)" ::: "memory");
  __syncthreads();

  {
    f32x4 yacc[2][16];
    #pragma unroll
    for (int m = 0; m < 2; ++m)
      #pragma unroll
      for (int n = 0; n < 16; ++n) yacc[m][n] = f32x4{0.f, 0.f, 0.f, 0.f};

    #pragma unroll
    for (int kk = 0; kk < 2; ++kk) {
      bf16x8 av[2];
      #pragma unroll
      for (int m = 0; m < 2; ++m) {
        int r = wr * 32 + m * 16 + lr;
        int c = (kk * 4 + lq) ^ (r & 7);
        av[m] = *reinterpret_cast<const bf16x8*>(&Hs[r * 64 + c * 8]);
      }
      #pragma unroll
      for (int n = 0; n < 16; ++n) {
        int r = wc * 256 + n * 16 + lr;
        int c = (kk * 4 + lq) ^ (r & 7);
        bf16x8 bv = *reinterpret_cast<const bf16x8*>(&sm[r * 64 + c * 8]);
        #pragma unroll
        for (int m = 0; m < 2; ++m)
          yacc[m][n] = __builtin_amdgcn_mfma_f32_16x16x32_bf16(av[m], bv, yacc[m][n], 0, 0, 0);
      }
    }

    float* Yo = Yp + (size_t)tj * RowsC * Dd;
    #pragma unroll
    for (int m = 0; m < 2; ++m) {
      int gr0 = bm + wr * 32 + m * 16 + lq * 4;
      #pragma unroll
      for (int n = 0; n < 16; ++n) {
        int gc = wc * 256 + n * 16 + lr;
        #pragma unroll
        for (int q = 0; q < 4; ++q)
          Yo[(size_t)(gr0 + q) * Dd + gc] = yacc[m][n][q];
      }
    }
  }
}

// S4: dH GEMM (blk 0-63) + colsum/ln (blk 64-65) + w1 grad+update (blk 66-193)
__global__ __launch_bounds__(256) void s4_k(
    const u16* __restrict__ dYb, const u16* __restrict__ w1t_cur,
    const u16* __restrict__ dZb, u16* dHtW, u16* dHtE,
    const float* __restrict__ gyr, float* lnc, float* Sln,
    const u16* __restrict__ dYtW, const u16* __restrict__ dYtE,
    const u16* __restrict__ Ht,
    float* w1c, float* Sw1, u16* w1b_new, u16* w1t_new,
    const float* wB, const float* wE, const float* scal)
{
  __shared__ __align__(16) u16 sm[6 * 64 * 128];
  int j = blockIdx.x;
  if (j < 64) {
    int tm = j & 3, tn = j >> 2;
    tile64<128, 2, 3>(sm, sm + 2 * 64 * 128, dYb, w1t_cur, Dd, Ii,
                      tm * 64, tn * 64,
                      nullptr, dHtW, dHtE, dZb, wB, wE, RowsC);
  } else if (j < 66) {
    int d = (j - 64) * 256 + threadIdx.x;
    float sm2 = 0.f, se2 = 0.f;
    for (int r = 0; r < RowsC; ++r) {
      float vv = gyr[(size_t)r * Dd + d];
      sm2 += wB[r] * vv; se2 += wE[r] * vv;
    }
    float pp = lnc[d], sn = Sln[d];
    lnc[d] = scal[0] * pp + scal[1] * sn - sm2;
    Sln[d] = scal[2] * sn - se2;
  } else {
    int q = j - 66;
    gtile64<128, 2, true>(sm, sm + 2 * 64 * 128, sm + 4 * 64 * 128,
                          dYtW, dYtE, Ht, w1c, Sw1, w1b_new, w1t_new,
                          scal, Dd, Ii, RowsC, (q >> 4) * 64, (q & 15) * 64);
  }
}

// w0 grad + update [grid 128]
__global__ __launch_bounds__(256) void g2b_k(
    const u16* __restrict__ dHtW, const u16* __restrict__ dHtE,
    const u16* __restrict__ KTc,
    float* w0c, float* Sw0, u16* w0b, const float* scal)
{
  __shared__ __align__(16) u16 sm[6 * 64 * 128];
  int j = blockIdx.x;
  gtile64<128, 2, false>(sm, sm + 2 * 64 * 128, sm + 4 * 64 * 128,
                         dHtW, dHtE, KTc, w0c, Sw0, w0b, nullptr,
                         scal, Ii, Dd, RowsC, (j >> 3) * 64, (j & 7) * 64);
}

// KVQ: V tiles (0-255), K row-complete (256-287), Q row-complete (288-319),
// gate scans (320-327)
__global__ __launch_bounds__(256) void kvq_k(
    const u16* __restrict__ xcb, const u16* __restrict__ wkvqb,
    float* Krows, u16* Kb, u16* KT, float* Vrows,
    float* Qb, u16* Qbb,
    const float* __restrict__ kn, const float* __restrict__ qn, char* ws)
{
  __shared__ __align__(16) u16 sm[2 * 64 * 32 + 2 * 512 * 32];  // 72 KB
  int j = blockIdx.x;
  if (j < 256) {
    int tn = j & 7, tm = j >> 3;
    tile64<128, 2, 5>(sm, sm + 2 * 64 * 128, xcb, wkvqb + (size_t)Dd * Dd,
                      Dd, Dd, tm * 64, tn * 64,
                      Vrows, nullptr, nullptr, nullptr, nullptr, nullptr, 0);
    return;
  }
  if (j < 288) {
    rowgemm<Dd, 0>(sm, xcb, wkvqb, (j - 256) * 64,
                   Krows, Kb, KT, kn, nullptr, nullptr);
    return;
  }
  if (j < 320) {
    rowgemm<Dd, 1>(sm, xcb, wkvqb + (size_t)2 * Dd * Dd, (j - 288) * 64,
                   Qb, Qbb, nullptr, qn, nullptr, nullptr);
    return;
  }
  if (threadIdx.x != 0) return;
  WS S = mkws(ws);
  int ci = j - 320;
  const float* alc = S.alv + ci * Cc;
  const float* etc_ = S.etv + ci * Cc;
  float beta[Cc], wb[Cc], ce[Cc], E[Cc], T[Cc];
  for (int i = 0; i < Cc; ++i) beta[i] = 1.f - alc[i];
  wb[Cc - 1] = 1.f;
  for (int m = Cc - 2; m >= 0; --m) wb[m] = wb[m + 1] * beta[m + 1];
  float bc_last = wb[0] * beta[0];
  float p = 1.f, A = 0.f;
  for (int m = 0; m < Cc; ++m) { p *= etc_[m]; ce[m] = p; A += wb[m] * ce[m]; }
  E[Cc - 1] = 1.f; T[Cc - 1] = 1.f;
  for (int n = Cc - 2; n >= 0; --n) {
    E[n] = E[n + 1] * etc_[n + 1];
    T[n] = wb[n] + etc_[n + 1] * T[n + 1];
  }
  for (int b = 0; b < Bb; ++b)
    for (int t = 0; t < Cc; ++t) {
      S.wBv[ci * RowsC + b * Cc + t] = T[t];
      S.wEv[ci * RowsC + b * Cc + t] = E[t];
    }
  S.scal[ci * 4 + 0] = bc_last; S.scal[ci * 4 + 1] = A; S.scal[ci * 4 + 2] = ce[Cc - 1];
}

// retrieval final: Yr row-complete GEMM + fused q + rms(y)*ln (grid 32)
__global__ __launch_bounds__(256) void yfin_k(
    const u16* __restrict__ Hrb, const u16* __restrict__ w1b,
    const float* __restrict__ Qb, const float* __restrict__ lnc,
    float* __restrict__ out)
{
  __shared__ __align__(16) u16 sm[2 * 64 * 32 + 2 * 512 * 32];  // 72 KB
  rowgemm<Ii, 2>(sm, Hrb, w1b, blockIdx.x * 64,
                 nullptr, nullptr, nullptr, lnc, Qb, out);
}

// 128x128-tile GEMM (2-phase dbuf) for retrieval Hr (silu epilogue)
__global__ __launch_bounds__(256) void mgemm128s_k(
    const u16* __restrict__ A, const u16* __restrict__ Bt,
    u16* Cb, int M, int N, int K)
{
  constexpr int TS = 128, BK = 64;
  constexpr int BUF = TS * BK;
  __shared__ __align__(16) u16 As[2 * BUF];
  __shared__ __align__(16) u16 Bs[2 * BUF];
  const int tid = threadIdx.x;
  const int l = tid & 63, lr = l & 15, lq = l >> 4;
  const int w = tid >> 6, wr = w >> 1, wc = w & 1;
  const int bm = blockIdx.y * TS, bn = blockIdx.x * TS;

  f32x4 acc[4][4];
  #pragma unroll
  for (int i = 0; i < 4; ++i)
    #pragma unroll
    for (int j = 0; j < 4; ++j) acc[i][j] = f32x4{0.f, 0.f, 0.f, 0.f};

  auto stage = [&](int k0, int buf) {
    u16* dA = As + buf * BUF;
    u16* dB = Bs + buf * BUF;
    #pragma unroll
    for (int i = 0; i < 4; ++i) {
      int e = i * 256 + tid;
      int r = e >> 3, c = (e & 7) ^ (r & 7);
      llds16(A  + (size_t)(bm + r) * K + k0 + c * 8, dA + e * 8);
      llds16(Bt + (size_t)(bn + r) * K + k0 + c * 8, dB + e * 8);
    }
  };

  stage(0, 0);
  drain_barrier();
  const int nt = K / BK;
  int cur = 0;
  for (int t = 0; t < nt; ++t) {
    if (t + 1 < nt) stage((t + 1) * BK, cur ^ 1);
    const u16* sA = As + cur * BUF;
    const u16* sB = Bs + cur * BUF;
    #pragma unroll
    for (int kk = 0; kk < 2; ++kk) {
      bf16x8 av[4], bv[4];
      #pragma unroll
      for (int m = 0; m < 4; ++m) {
        int r = wr * 64 + m * 16 + lr;
        int c = (kk * 4 + lq) ^ (r & 7);
        av[m] = *reinterpret_cast<const bf16x8*>(&sA[r * BK + c * 8]);
      }
      #pragma unroll
      for (int n = 0; n < 4; ++n) {
        int r = wc * 64 + n * 16 + lr;
        int c = (kk * 4 + lq) ^ (r & 7);
        bv[n] = *reinterpret_cast<const bf16x8*>(&sB[r * BK + c * 8]);
      }
      #pragma unroll
      for (int m = 0; m < 4; ++m)
        #pragma unroll
        for (int n = 0; n < 4; ++n)
          acc[m][n] = __builtin_amdgcn_mfma_f32_16x16x32_bf16(av[m], bv[n], acc[m][n], 0, 0, 0);
    }
    drain_barrier();
    cur ^= 1;
  }

  #pragma unroll
  for (int m = 0; m < 4; ++m) {
    int gr0 = bm + wr * 64 + m * 16 + lq * 4;
    #pragma unroll
    for (int n = 0; n < 4; ++n) {
      int gc = bn + wc * 64 + n * 16 + lr;
      #pragma unroll
      for (int q = 0; q < 4; ++q)
        Cb[(size_t)(gr0 + q) * N + gc] = f2bf(siluf_(acc[m][n][q]));
    }
  }
}

// init: prep (blk 0-511) + w1^T (blk 512-639) + converts (blk 640-1151)
__global__ __launch_bounds__(256) void init_k(
    const float* __restrict__ x,
    const float* __restrict__ aw, const float* __restrict__ ab,
    const float* __restrict__ tw, const float* __restrict__ tb,
    const float* __restrict__ ew, const float* __restrict__ eb,
    const float* __restrict__ wq, const float* __restrict__ wkw,
    const float* __restrict__ wvw, const float* __restrict__ mw0,
    const float* __restrict__ mw1, const float* __restrict__ mln,
    char* ws)
{
  WS S = mkws(ws);
  const int tid = threadIdx.x;
  if (blockIdx.x < 512) {
    __shared__ float red[256];
    int s = blockIdx.x;
    int ci = s >> 6, t = s & 63;
    float sa = 0.f, st = 0.f, se = 0.f;
    for (int b = 0; b < Bb; ++b) {
      const float* xr = x + ((size_t)b * Ss + s) * Dd;
      u16* dst = S.xcb + ((size_t)(ci * RowsC + b * Cc + t)) * Dd;
      for (int d = tid; d < Dd; d += 256) {
        float v = xr[d];
        dst[d] = f2bf(v);
        sa += v * aw[d]; st += v * tw[d]; se += v * ew[d];
      }
    }
    sa = block_reduce_sum(sa, red);
    st = block_reduce_sum(st, red);
    se = block_reduce_sum(se, red);
    if (tid == 0) {
      S.alv[s] = sigmoidf_(sa + Bb * ab[0]);
      S.thv[s] = sigmoidf_(st + Bb * tb[0]) * 0.01f;
      S.etv[s] = sigmoidf_(se + Bb * eb[0]);
    }
    return;
  }
  if (blockIdx.x < 640) {
    __shared__ float t[64][65];
    int tt = blockIdx.x - 512;
    int br = (tt & 7) * 64, bc = (tt >> 3) * 64;
    #pragma unroll
    for (int i = 0; i < 16; ++i) {
      int e = tid + i * 256;
      int r = e >> 6, c = e & 63;
      t[r][c] = mw1[(size_t)(br + r) * Ii + bc + c];
    }
    __syncthreads();
    #pragma unroll
    for (int i = 0; i < 16; ++i) {
      int e = tid + i * 256;
      int rr = e >> 6, cc = e & 63;
      S.w1tb[(size_t)(bc + rr) * Dd + br + cc] = f2bf(t[cc][rr]);
    }
    return;
  }
  const int i0 = (blockIdx.x - 640) * 256 + tid;
  const int stride = 512 * 256;
  for (int i = i0; i < (Dd * Dd) / 4; i += stride) {
    float4 v = ((const float4*)wkw)[i];
    ushort4 o; o.x = f2bf(v.x); o.y = f2bf(v.y); o.z = f2bf(v.z); o.w = f2bf(v.w);
    ((ushort4*)S.wkvqb)[i] = o;
    v = ((const float4*)wvw)[i];
    o.x = f2bf(v.x); o.y = f2bf(v.y); o.z = f2bf(v.z); o.w = f2bf(v.w);
    ((ushort4*)S.wkvqb)[i + (Dd * Dd) / 4] = o;
    v = ((const float4*)wq)[i];
    o.x = f2bf(v.x); o.y = f2bf(v.y); o.z = f2bf(v.z); o.w = f2bf(v.w);
    ((ushort4*)S.wkvqb)[i + (Dd * Dd) / 2] = o;
  }
  for (int i = i0; i < (Ii * Dd) / 4; i += stride) {
    float4 z4; z4.x = z4.y = z4.z = z4.w = 0.f;
    float4 v = ((const float4*)mw0)[i];
    ((float4*)S.w0c)[i] = v; ((float4*)S.Sw0)[i] = z4;
    ushort4 o; o.x = f2bf(v.x); o.y = f2bf(v.y); o.z = f2bf(v.z); o.w = f2bf(v.w);
    ((ushort4*)S.w0b)[i] = o;
    v = ((const float4*)mw1)[i];
    ((float4*)S.w1c)[i] = v; ((float4*)S.Sw1)[i] = z4;
    o.x = f2bf(v.x); o.y = f2bf(v.y); o.z = f2bf(v.z); o.w = f2bf(v.w);
    ((ushort4*)S.w1b)[i] = o;
  }
  for (int i = i0; i < Dd; i += stride) { S.lnc[i] = mln[i]; S.Sln[i] = 0.f; }
}

// wave-per-row loss backward (sums 16 split-K Y partials)
__global__ __launch_bounds__(256) void loss_back4_k(
    const float* __restrict__ Kr, const float* __restrict__ Vr,
    const float* __restrict__ Yp, const float* __restrict__ lnc,
    const float* __restrict__ th, const float* __restrict__ wB,
    const float* __restrict__ wE,
    u16* __restrict__ dYb, u16* __restrict__ dYtW, u16* __restrict__ dYtE,
    float* __restrict__ gyr)
{
  __shared__ u16 lw[4][Dd];
  __shared__ u16 le[4][Dd];
  const int tid = threadIdx.x, w = tid >> 6, l = tid & 63;
  const int row = blockIdx.x * 4 + w, t = row & 63, d0 = l * 8;
  size_t base = (size_t)row * Dd + d0;

  float y[8] = {0.f, 0.f, 0.f, 0.f, 0.f, 0.f, 0.f, 0.f};
  #pragma unroll
  for (int p2 = 0; p2 < 16; ++p2) {
    const float* yp = Yp + (size_t)p2 * (RowsC * Dd) + base;
    float4 u0 = *(const float4*)yp;
    float4 u1 = *(const float4*)(yp + 4);
    y[0] += u0.x; y[1] += u0.y; y[2] += u0.z; y[3] += u0.w;
    y[4] += u1.x; y[5] += u1.y; y[6] += u1.z; y[7] += u1.w;
  }

  float kk[8], vv[8], lv[8];
  *(float4*)&kk[0] = *(const float4*)(Kr + base);
  *(float4*)&kk[4] = *(const float4*)(Kr + base + 4);
  *(float4*)&vv[0] = *(const float4*)(Vr + base);
  *(float4*)&vv[4] = *(const float4*)(Vr + base + 4);
  *(float4*)&lv[0] = *(const float4*)(lnc + d0);
  *(float4*)&lv[4] = *(const float4*)(lnc + d0 + 4);

  float ss = 0.f;
  #pragma unroll
  for (int q = 0; q < 8; ++q) ss += y[q] * y[q];
  ss = wave_sum(ss);
  float rr = rsqrtf(ss / (float)Dd + EPS);
  float c = 2.f * th[t] / (float)Dd;

  float g[8], s2 = 0.f;
  #pragma unroll
  for (int q = 0; q < 8; ++q) {
    g[q] = c * ((kk[q] + y[q] * rr * lv[q]) - vv[q]);
    s2 += g[q] * lv[q] * y[q];
  }
  s2 = wave_sum(s2);
  float coef = rr * rr * rr * s2 / (float)Dd;

  float wb = wB[row], we = wE[row];
  u16x8 pb; float gy[8];
  #pragma unroll
  for (int q = 0; q < 8; ++q) {
    float dv = rr * g[q] * lv[q] - coef * y[q];
    pb[q] = f2bf(dv);
    lw[w][d0 + q] = f2bf(dv * wb);
    le[w][d0 + q] = f2bf(dv * we);
    gy[q] = g[q] * y[q] * rr;
  }
  *(u16x8*)(dYb + base) = pb;
  *(float4*)(gyr + base)     = *(float4*)&gy[0];
  *(float4*)(gyr + base + 4) = *(float4*)&gy[4];

  __syncthreads();
  int r0 = blockIdx.x * 4;
  for (int d = tid; d < Dd; d += 256) {
    ushort4 pw, pe;
    pw.x = lw[0][d]; pw.y = lw[1][d]; pw.z = lw[2][d]; pw.w = lw[3][d];
    pe.x = le[0][d]; pe.y = le[1][d]; pe.z = le[2][d]; pe.w = le[3][d];
    *reinterpret_cast<ushort4*>(&dYtW[(size_t)d * RowsC + r0]) = pw;
    *reinterpret_cast<ushort4*>(&dYtE[(size_t)d * RowsC + r0]) = pe;
  }
}

} // namespace

extern "C" void kernel_launch(void* const* d_in, const int* in_sizes, int n_in,
                              void* d_out, int out_size, void* d_ws, size_t ws_size,
                              hipStream_t stream)
{
  const float* x   = (const float*)d_in[0];
  const float* wq  = (const float*)d_in[1];
  const float* wkw = (const float*)d_in[2];
  const float* wvw = (const float*)d_in[3];
  const float* qn  = (const float*)d_in[4];
  const float* kn  = (const float*)d_in[5];
  const float* aw  = (const float*)d_in[6];
  const float* ab  = (const float*)d_in[7];
  const float* tw  = (const float*)d_in[8];
  const float* tb  = (const float*)d_in[9];
  const float* ew  = (const float*)d_in[10];
  const float* eb  = (const float*)d_in[11];
  const float* mw0 = (const float*)d_in[12];
  const float* mw1 = (const float*)d_in[13];
  const float* mln = (const float*)d_in[14];
  float* out = (float*)d_out;
  char* ws = (char*)d_ws;
  WS S = mkws(ws);

  // ---- init (prep + transpose + converts); kvq fuses V/K/Q + norms + scans
  init_k<<<1152, 256, 0, stream>>>(x, aw, ab, tw, tb, ew, eb,
                                   wq, wkw, wvw, mw0, mw1, mln, ws);
  kvq_k<<<328, 256, 0, stream>>>(S.xcb, S.wkvqb, S.Krows, S.Kb, S.KT,
                                 S.Vrows, S.Qb, S.Qbb, kn, qn, ws);

  // ---- sequential chunk loop: 4 launches per chunk ----
  for (int ci = 0; ci < nCk; ++ci) {
    const int p = ci & 1;
    const u16* Kbc = S.Kb + (size_t)ci * RowsC * Dd;
    const u16* KTc = S.KT + (size_t)ci * Dd * RowsC;
    const float* Krc = S.Krows + (size_t)ci * RowsC * Dd;
    const float* Vrc = S.Vrows + (size_t)ci * RowsC * Dd;
    const float* scc = S.scal + ci * 4;
    const float* wBc = S.wBv + ci * RowsC;
    const float* wEc = S.wEv + ci * RowsC;
    const float* thc = S.thv + ci * Cc;
    u16* w1b_cur = S.w1b + (size_t)p * Dd * Ii;
    u16* w1b_new = S.w1b + (size_t)(p ^ 1) * Dd * Ii;
    u16* w1t_cur = S.w1tb + (size_t)p * Ii * Dd;
    u16* w1t_new = S.w1tb + (size_t)(p ^ 1) * Ii * Dd;

    z0y_k<<<dim3(16, 4), 256, 0, stream>>>(
        Kbc, S.w0b, w1b_cur, S.Ht, S.dZb, S.Yp);
    loss_back4_k<<<RowsC / 4, 256, 0, stream>>>(
        Krc, Vrc, S.Yp, S.lnc, thc, wBc, wEc, S.dYb, S.dYtW, S.dYtE, S.gyr);
    s4_k<<<194, 256, 0, stream>>>(
        S.dYb, w1t_cur, S.dZb, S.dHtW, S.dHtE, S.gyr, S.lnc, S.Sln,
        S.dYtW, S.dYtE, S.Ht, S.w1c, S.Sw1, w1b_new, w1t_new,
        wBc, wEc, scc);
    g2b_k<<<128, 256, 0, stream>>>(
        S.dHtW, S.dHtE, KTc, S.w0c, S.Sw0, S.w0b, scc);
  }

  // ---- retrieval: Hr GEMM, then row-complete Y + fused final ----
  mgemm128s_k<<<dim3(Ii / 128, RowsAll / 128), 256, 0, stream>>>(
      S.Qbb, S.w0b, S.Hrb, RowsAll, Ii, Dd);
  yfin_k<<<RowsAll / 64, 256, 0, stream>>>(S.Hrb, S.w1b, S.Qb, S.lnc, out);
}

// Round 11
// 386.454 us; speedup vs baseline: 1.0679x; 1.0679x over previous
//
#include <hip/hip_runtime.h>
#include <math.h>

#define EPS 1e-6f

namespace {

typedef unsigned short u16;
typedef unsigned int u32;
typedef __bf16 bf16x8 __attribute__((ext_vector_type(8)));
typedef float f32x4 __attribute__((ext_vector_type(4)));
typedef u16 u16x8 __attribute__((ext_vector_type(8)));

constexpr int Bb = 4, Ss = 512, Dd = 512, Ii = 1024, Cc = 64;
constexpr int nCk = 8, RowsC = 256, RowsAll = 2048;

__device__ __forceinline__ float sigmoidf_(float x) { return 1.f / (1.f + expf(-x)); }
__device__ __forceinline__ float siluf_(float x)    { return x / (1.f + expf(-x)); }

__device__ __forceinline__ u16 f2bf(float f) {
  u32 u = __float_as_uint(f);
  u32 r = u + 0x7fffu + ((u >> 16) & 1u);
  return (u16)(r >> 16);
}
__device__ __forceinline__ float bf2f(u16 u) {
  return __uint_as_float(((u32)u) << 16);
}

__device__ __forceinline__ void llds16(const u16* g, u16* l) {
  __builtin_amdgcn_global_load_lds((__attribute__((address_space(1))) void*)g,
                                   (__attribute__((address_space(3))) void*)l,
                                   16, 0, 0);
}

__device__ __forceinline__ void drain_barrier() {
  asm volatile("s_waitcnt vmcnt(0)" ::: "memory");
  __builtin_amdgcn_s_barrier();
}

__device__ __forceinline__ float wave_sum(float v) {
  #pragma unroll
  for (int m = 32; m > 0; m >>= 1) v += __shfl_xor(v, m, 64);
  return v;
}

__device__ __forceinline__ float block_reduce_sum(float v, float* red) {
  int tid = threadIdx.x;
  red[tid] = v; __syncthreads();
  for (int s = 128; s > 0; s >>= 1) {
    if (tid < s) red[tid] += red[tid + s];
    __syncthreads();
  }
  float r = red[0]; __syncthreads();
  return r;
}

// ---------------- workspace carve ----------------
struct WS {
  float *w0c, *Sw0, *w1c, *Sw1, *lnc, *Sln, *tmpK, *Krows, *Vrows,
        *Yp, *gyr, *alv, *thv, *etv, *wBv, *wEv, *scal, *Qb, *Yr;
  u16 *xcb, *wkvqb, *w0b, *w1b, *w1tb, *Kb, *KT, *Ht, *dZb,
      *dYb, *dYtW, *dYtE, *dHtW, *dHtE, *Qbb, *Hrb;
};
__host__ __device__ inline WS mkws(char* base) {
  WS s; char* p = base + 256;
#define CF(nm, n) s.nm = (float*)p; p += (size_t)(n) * 4;
#define CU(nm, n) s.nm = (u16*)p;   p += (size_t)(n) * 2;
  CF(w0c, Ii*Dd) CF(Sw0, Ii*Dd) CF(w1c, Dd*Ii) CF(Sw1, Dd*Ii)
  CF(lnc, Dd) CF(Sln, Dd)
  CF(tmpK, (size_t)RowsAll*Dd) CF(Krows, (size_t)RowsAll*Dd) CF(Vrows, (size_t)RowsAll*Dd)
  CF(Yp, (size_t)16*RowsC*Dd) CF(gyr, RowsC*Dd)
  CF(alv, Ss) CF(thv, Ss) CF(etv, Ss) CF(wBv, nCk*RowsC) CF(wEv, nCk*RowsC) CF(scal, nCk*4)
  CF(Qb, (size_t)RowsAll*Dd) CF(Yr, (size_t)RowsAll*Dd)
  CU(xcb, (size_t)RowsAll*Dd) CU(wkvqb, (size_t)3*Dd*Dd)
  CU(w0b, (size_t)Ii*Dd) CU(w1b, (size_t)2*Dd*Ii) CU(w1tb, (size_t)2*Ii*Dd)
  CU(Kb, (size_t)RowsAll*Dd) CU(KT, (size_t)RowsAll*Dd)
  CU(Ht, RowsC*Ii) CU(dZb, RowsC*Ii)
  CU(dYb, RowsC*Dd) CU(dYtW, RowsC*Dd) CU(dYtE, RowsC*Dd)
  CU(dHtW, RowsC*Ii) CU(dHtE, RowsC*Ii)
  CU(Qbb, (size_t)RowsAll*Dd) CU(Hrb, (size_t)RowsAll*Ii)
#undef CF
#undef CU
  return s;
}

// ---------------- 64x64 MFMA tile, BK/NBUF-param ----------------
// EPI: 0 C0=v
//      1 KVQ split: gc<512->C0=v | gc<1024->C1=silu(v) | else C2=v (all ld=Dd)
//      3 dh=v*bf2f(Zb): CbT=bf(dh*wB)^T, CbT2=bf(dh*wE)^T
template<int BK, int NBUF, int EPI>
__device__ void tile64(
    u16* smA, u16* smB,
    const u16* __restrict__ A, const u16* __restrict__ Bt,
    int K, int N, int bm, int bn,
    float* C0, float* C1, float* C2,
    u16* CbT, u16* CbT2,
    const u16* Zb, const float* wB, const float* wE, int trM)
{
  constexpr int CPR = BK / 8;
  constexpr int NISS = (64 * CPR) / 256;
  constexpr int BUF = 64 * BK;
  const int tid = threadIdx.x;
  const int l = tid & 63, lr = l & 15, lq = l >> 4;
  const int w = tid >> 6, wr = w >> 1, wc = w & 1;

  f32x4 acc[2][2];
  #pragma unroll
  for (int i = 0; i < 2; ++i)
    #pragma unroll
    for (int j = 0; j < 2; ++j) acc[i][j] = f32x4{0.f, 0.f, 0.f, 0.f};

  auto stage = [&](int k0, int buf) {
    u16* dA = smA + buf * BUF;
    u16* dB = smB + buf * BUF;
    #pragma unroll
    for (int i = 0; i < NISS; ++i) {
      int e = i * 256 + tid;
      int r = e / CPR, c = (e & (CPR - 1)) ^ (r & (CPR - 1));
      llds16(A  + (size_t)(bm + r) * K + k0 + c * 8, dA + e * 8);
      llds16(Bt + (size_t)(bn + r) * K + k0 + c * 8, dB + e * 8);
    }
  };

  stage(0, 0);
  drain_barrier();
  const int nt = K / BK;
  int cur = 0;
  for (int t = 0; t < nt; ++t) {
    if (t + 1 < nt) stage((t + 1) * BK, (cur ^ 1) & (NBUF - 1));
    const u16* sA = smA + cur * BUF;
    const u16* sB = smB + cur * BUF;
    #pragma unroll
    for (int kk = 0; kk < BK / 32; ++kk) {
      bf16x8 av[2], bv[2];
      #pragma unroll
      for (int m = 0; m < 2; ++m) {
        int r = wr * 32 + m * 16 + lr;
        int c = (kk * 4 + lq) ^ (r & (CPR - 1));
        av[m] = *reinterpret_cast<const bf16x8*>(&sA[r * BK + c * 8]);
      }
      #pragma unroll
      for (int n = 0; n < 2; ++n) {
        int r = wc * 32 + n * 16 + lr;
        int c = (kk * 4 + lq) ^ (r & (CPR - 1));
        bv[n] = *reinterpret_cast<const bf16x8*>(&sB[r * BK + c * 8]);
      }
      #pragma unroll
      for (int m = 0; m < 2; ++m)
        #pragma unroll
        for (int n = 0; n < 2; ++n)
          acc[m][n] = __builtin_amdgcn_mfma_f32_16x16x32_bf16(av[m], bv[n], acc[m][n], 0, 0, 0);
    }
    drain_barrier();
    cur = (cur ^ 1) & (NBUF - 1);
  }

  #pragma unroll
  for (int m = 0; m < 2; ++m) {
    int gr0 = bm + wr * 32 + m * 16 + lq * 4;
    float wbq[4], weq[4];
    if (EPI == 3) {
      #pragma unroll
      for (int q = 0; q < 4; ++q) { wbq[q] = wB[gr0 + q]; weq[q] = wE[gr0 + q]; }
    }
    #pragma unroll
    for (int n = 0; n < 2; ++n) {
      int gc = bn + wc * 32 + n * 16 + lr;
      ushort4 t1, t2;
      #pragma unroll
      for (int q = 0; q < 4; ++q) {
        float v = acc[m][n][q];
        size_t idx = (size_t)(gr0 + q) * N + gc;
        if (EPI == 0) {
          C0[idx] = v;
        } else if (EPI == 1) {
          size_t rb = (size_t)(gr0 + q) * Dd;
          if (gc < Dd)            C0[rb + gc] = v;
          else if (gc < 2 * Dd)   C1[rb + gc - Dd] = siluf_(v);
          else                    C2[rb + gc - 2 * Dd] = v;
        } else if (EPI == 3) {
          float dh = v * bf2f(Zb[idx]);
          ((u16*)&t1)[q] = f2bf(dh * wbq[q]);
          ((u16*)&t2)[q] = f2bf(dh * weq[q]);
        }
      }
      if (EPI == 3) {
        *reinterpret_cast<ushort4*>(&CbT[(size_t)gc * trM + gr0]) = t1;
        *reinterpret_cast<ushort4*>(&CbT2[(size_t)gc * trM + gr0]) = t2;
      }
    }
  }
}

// ------------- dual-weighted grad tile + fused param update -----------
template<int BK, int NBUF, bool TR>
__device__ void gtile64(
    u16* smA, u16* smB, u16* smE,
    const u16* __restrict__ AW, const u16* __restrict__ AE,
    const u16* __restrict__ Bt,
    float* P, float* Sm, u16* Pb, u16* PbT, const float* scal,
    int M, int N, int K, int bm, int bn)
{
  constexpr int CPR = BK / 8;
  constexpr int NISS = (64 * CPR) / 256;
  constexpr int BUF = 64 * BK;
  const int tid = threadIdx.x;
  const int l = tid & 63, lr = l & 15, lq = l >> 4;
  const int w = tid >> 6, wr = w >> 1, wc = w & 1;

  f32x4 aM[2][2], aE[2][2];
  #pragma unroll
  for (int i = 0; i < 2; ++i)
    #pragma unroll
    for (int j = 0; j < 2; ++j) {
      aM[i][j] = f32x4{0.f, 0.f, 0.f, 0.f};
      aE[i][j] = f32x4{0.f, 0.f, 0.f, 0.f};
    }

  auto stage = [&](int k0, int buf) {
    u16* dA = smA + buf * BUF;
    u16* dE = smE + buf * BUF;
    u16* dB = smB + buf * BUF;
    #pragma unroll
    for (int i = 0; i < NISS; ++i) {
      int e = i * 256 + tid;
      int r = e / CPR, c = (e & (CPR - 1)) ^ (r & (CPR - 1));
      llds16(AW + (size_t)(bm + r) * K + k0 + c * 8, dA + e * 8);
      llds16(AE + (size_t)(bm + r) * K + k0 + c * 8, dE + e * 8);
      llds16(Bt + (size_t)(bn + r) * K + k0 + c * 8, dB + e * 8);
    }
  };

  stage(0, 0);
  drain_barrier();
  const int nt = K / BK;
  int cur = 0;
  for (int t = 0; t < nt; ++t) {
    if (t + 1 < nt) stage((t + 1) * BK, (cur ^ 1) & (NBUF - 1));
    const u16* sA = smA + cur * BUF;
    const u16* sE = smE + cur * BUF;
    const u16* sB = smB + cur * BUF;
    #pragma unroll
    for (int kk = 0; kk < BK / 32; ++kk) {
      bf16x8 awv[2], aev[2], bv[2];
      #pragma unroll
      for (int m = 0; m < 2; ++m) {
        int r = wr * 32 + m * 16 + lr;
        int c = (kk * 4 + lq) ^ (r & (CPR - 1));
        awv[m] = *reinterpret_cast<const bf16x8*>(&sA[r * BK + c * 8]);
        aev[m] = *reinterpret_cast<const bf16x8*>(&sE[r * BK + c * 8]);
      }
      #pragma unroll
      for (int n = 0; n < 2; ++n) {
        int r = wc * 32 + n * 16 + lr;
        int c = (kk * 4 + lq) ^ (r & (CPR - 1));
        bv[n] = *reinterpret_cast<const bf16x8*>(&sB[r * BK + c * 8]);
      }
      #pragma unroll
      for (int m = 0; m < 2; ++m)
        #pragma unroll
        for (int n = 0; n < 2; ++n) {
          aM[m][n] = __builtin_amdgcn_mfma_f32_16x16x32_bf16(awv[m], bv[n], aM[m][n], 0, 0, 0);
          aE[m][n] = __builtin_amdgcn_mfma_f32_16x16x32_bf16(aev[m], bv[n], aE[m][n], 0, 0, 0);
        }
    }
    drain_barrier();
    cur = (cur ^ 1) & (NBUF - 1);
  }

  float s0 = scal[0], s1 = scal[1], s2 = scal[2];
  #pragma unroll
  for (int m = 0; m < 2; ++m) {
    int gr0 = bm + wr * 32 + m * 16 + lq * 4;
    #pragma unroll
    for (int n = 0; n < 2; ++n) {
      int gc = bn + wc * 32 + n * 16 + lr;
      ushort4 t1;
      #pragma unroll
      for (int q = 0; q < 4; ++q) {
        size_t idx = (size_t)(gr0 + q) * N + gc;
        float p = P[idx], s = Sm[idx];
        float np = s0 * p + s1 * s - aM[m][n][q];
        float ns = s2 * s - aE[m][n][q];
        P[idx] = np; Sm[idx] = ns;
        Pb[idx] = f2bf(np);
        if (TR) ((u16*)&t1)[q] = f2bf(np);
      }
      if (TR) *reinterpret_cast<ushort4*>(&PbT[(size_t)gc * M + gr0]) = t1;
    }
  }
}

// ---------------- kernels ----------------

// Fused Z0 + split-K partial Y.
__global__ __launch_bounds__(256) void z0y_k(
    const u16* __restrict__ Kbc, const u16* __restrict__ w0b,
    const u16* __restrict__ w1b,
    u16* __restrict__ Ht, u16* __restrict__ dZb, float* __restrict__ Yp)
{
  __shared__ __align__(16) u16 sm[4 * 64 * 128 + 64 * 64];  // 72 KB
  u16* Hs = sm + 4 * 64 * 128;
  const int tid = threadIdx.x;
  const int l = tid & 63, lr = l & 15, lq = l >> 4;
  const int w = tid >> 6, wr = w >> 1, wc = w & 1;
  const int tj = blockIdx.x, tr = blockIdx.y;
  const int bm = tr * 64, bn = tj * 64;

  {
    constexpr int BK = 128, CPR = 16, NISS = 4, BUF = 64 * BK;
    u16* smA = sm; u16* smB = sm + 2 * BUF;
    f32x4 acc[2][2];
    #pragma unroll
    for (int i = 0; i < 2; ++i)
      #pragma unroll
      for (int j = 0; j < 2; ++j) acc[i][j] = f32x4{0.f, 0.f, 0.f, 0.f};

    auto stage = [&](int k0, int buf) {
      u16* dA = smA + buf * BUF;
      u16* dB = smB + buf * BUF;
      #pragma unroll
      for (int i = 0; i < NISS; ++i) {
        int e = i * 256 + tid;
        int r = e / CPR, c = (e & (CPR - 1)) ^ (r & (CPR - 1));
        llds16(Kbc + (size_t)(bm + r) * Dd + k0 + c * 8, dA + e * 8);
        llds16(w0b + (size_t)(bn + r) * Dd + k0 + c * 8, dB + e * 8);
      }
    };
    stage(0, 0);
    drain_barrier();
    int cur = 0;
    for (int t = 0; t < 4; ++t) {
      if (t + 1 < 4) stage((t + 1) * BK, cur ^ 1);
      const u16* sA = smA + cur * BUF;
      const u16* sB = smB + cur * BUF;
      #pragma unroll
      for (int kk = 0; kk < 4; ++kk) {
        bf16x8 av[2], bv[2];
        #pragma unroll
        for (int m = 0; m < 2; ++m) {
          int r = wr * 32 + m * 16 + lr;
          int c = (kk * 4 + lq) ^ (r & (CPR - 1));
          av[m] = *reinterpret_cast<const bf16x8*>(&sA[r * BK + c * 8]);
        }
        #pragma unroll
        for (int n = 0; n < 2; ++n) {
          int r = wc * 32 + n * 16 + lr;
          int c = (kk * 4 + lq) ^ (r & (CPR - 1));
          bv[n] = *reinterpret_cast<const bf16x8*>(&sB[r * BK + c * 8]);
        }
        #pragma unroll
        for (int m = 0; m < 2; ++m)
          #pragma unroll
          for (int n = 0; n < 2; ++n)
            acc[m][n] = __builtin_amdgcn_mfma_f32_16x16x32_bf16(av[m], bv[n], acc[m][n], 0, 0, 0);
      }
      drain_barrier();
      cur ^= 1;
    }

    #pragma unroll
    for (int i = 0; i < 16; ++i) {
      int e = i * 256 + tid;
      int r = e >> 3, c = (e & 7) ^ (r & 7);
      llds16(w1b + (size_t)r * Ii + bn + c * 8, sm + e * 8);
    }

    #pragma unroll
    for (int m = 0; m < 2; ++m) {
      int gr0 = bm + wr * 32 + m * 16 + lq * 4;
      int rl0 = wr * 32 + m * 16 + lq * 4;
      #pragma unroll
      for (int n = 0; n < 2; ++n) {
        int gc = bn + wc * 32 + n * 16 + lr;
        int cl = wc * 32 + n * 16 + lr;
        ushort4 t1;
        #pragma unroll
        for (int q = 0; q < 4; ++q) {
          float v = acc[m][n][q];
          float sg = 1.f / (1.f + expf(-v));
          float h = v * sg;
          float ds = sg * (1.f + v * (1.f - sg));
          u16 hb = f2bf(h);
          ((u16*)&t1)[q] = hb;
          dZb[(size_t)(gr0 + q) * Ii + gc] = f2bf(ds);
          int rl = rl0 + q;
          Hs[rl * 64 + ((((cl >> 3) ^ (rl & 7)) << 3) | (cl & 7))] = hb;
        }
        *reinterpret_cast<ushort4*>(&Ht[(size_t)gc * RowsC + gr0]) = t1;
      }
    }
  }

  asm volatile("s_waitcnt vmcnt(0)" ::: "memory");
  __syncthreads();

  {
    f32x4 yacc[2][16];
    #pragma unroll
    for (int m = 0; m < 2; ++m)
      #pragma unroll
      for (int n = 0; n < 16; ++n) yacc[m][n] = f32x4{0.f, 0.f, 0.f, 0.f};

    #pragma unroll
    for (int kk = 0; kk < 2; ++kk) {
      bf16x8 av[2];
      #pragma unroll
      for (int m = 0; m < 2; ++m) {
        int r = wr * 32 + m * 16 + lr;
        int c = (kk * 4 + lq) ^ (r & 7);
        av[m] = *reinterpret_cast<const bf16x8*>(&Hs[r * 64 + c * 8]);
      }
      #pragma unroll
      for (int n = 0; n < 16; ++n) {
        int r = wc * 256 + n * 16 + lr;
        int c = (kk * 4 + lq) ^ (r & 7);
        bf16x8 bv = *reinterpret_cast<const bf16x8*>(&sm[r * 64 + c * 8]);
        #pragma unroll
        for (int m = 0; m < 2; ++m)
          yacc[m][n] = __builtin_amdgcn_mfma_f32_16x16x32_bf16(av[m], bv, yacc[m][n], 0, 0, 0);
      }
    }

    float* Yo = Yp + (size_t)tj * RowsC * Dd;
    #pragma unroll
    for (int m = 0; m < 2; ++m) {
      int gr0 = bm + wr * 32 + m * 16 + lq * 4;
      #pragma unroll
      for (int n = 0; n < 16; ++n) {
        int gc = wc * 256 + n * 16 + lr;
        #pragma unroll
        for (int q = 0; q < 4; ++q)
          Yo[(size_t)(gr0 + q) * Dd + gc] = yacc[m][n][q];
      }
    }
  }
}

// S4: dH GEMM (blk 0-63) + colsum/ln (blk 64-65) + w1 grad+update (blk 66-193)
__global__ __launch_bounds__(256) void s4_k(
    const u16* __restrict__ dYb, const u16* __restrict__ w1t_cur,
    const u16* __restrict__ dZb, u16* dHtW, u16* dHtE,
    const float* __restrict__ gyr, float* lnc, float* Sln,
    const u16* __restrict__ dYtW, const u16* __restrict__ dYtE,
    const u16* __restrict__ Ht,
    float* w1c, float* Sw1, u16* w1b_new, u16* w1t_new,
    const float* wB, const float* wE, const float* scal)
{
  __shared__ __align__(16) u16 sm[6 * 64 * 128];
  int j = blockIdx.x;
  if (j < 64) {
    int tm = j & 3, tn = j >> 2;
    tile64<128, 2, 3>(sm, sm + 2 * 64 * 128, dYb, w1t_cur, Dd, Ii,
                      tm * 64, tn * 64,
                      nullptr, nullptr, nullptr, dHtW, dHtE,
                      dZb, wB, wE, RowsC);
  } else if (j < 66) {
    int d = (j - 64) * 256 + threadIdx.x;
    float sm2 = 0.f, se2 = 0.f;
    for (int r = 0; r < RowsC; ++r) {
      float vv = gyr[(size_t)r * Dd + d];
      sm2 += wB[r] * vv; se2 += wE[r] * vv;
    }
    float pp = lnc[d], sn = Sln[d];
    lnc[d] = scal[0] * pp + scal[1] * sn - sm2;
    Sln[d] = scal[2] * sn - se2;
  } else {
    int q = j - 66;                       // 128 tiles: M=Dd(8) x N=Ii(16)
    gtile64<128, 2, true>(sm, sm + 2 * 64 * 128, sm + 4 * 64 * 128,
                          dYtW, dYtE, Ht, w1c, Sw1, w1b_new, w1t_new,
                          scal, Dd, Ii, RowsC, (q >> 4) * 64, (q & 15) * 64);
  }
}

// w0 grad + update [grid 128]
__global__ __launch_bounds__(256) void g2b_k(
    const u16* __restrict__ dHtW, const u16* __restrict__ dHtE,
    const u16* __restrict__ KTc,
    float* w0c, float* Sw0, u16* w0b, const float* scal)
{
  __shared__ __align__(16) u16 sm[6 * 64 * 128];
  int j = blockIdx.x;                     // M=Ii(16) x N=Dd(8)
  gtile64<128, 2, false>(sm, sm + 2 * 64 * 128, sm + 4 * 64 * 128,
                         dHtW, dHtE, KTc, w0c, Sw0, w0b, nullptr,
                         scal, Ii, Dd, RowsC, (j >> 3) * 64, (j & 7) * 64);
}

// KVQ GEMM (blk 0-767) + per-chunk gate scans (blk 768-775)
__global__ __launch_bounds__(256) void kvq_k(
    const u16* __restrict__ xcb, const u16* __restrict__ wkvqb,
    float* tmpK, float* Vrows, float* Yq, char* ws)
{
  __shared__ __align__(16) u16 sm[4 * 64 * 128];
  int j = blockIdx.x;
  if (j < 768) {
    int tn = j % 24, tm = j / 24;
    tile64<128, 2, 1>(sm, sm + 2 * 64 * 128, xcb, wkvqb, Dd, 3 * Dd,
                      tm * 64, tn * 64,
                      tmpK, Vrows, Yq, nullptr, nullptr,
                      nullptr, nullptr, nullptr, 0);
    return;
  }
  if (threadIdx.x != 0) return;
  WS S = mkws(ws);
  int ci = j - 768;
  const float* alc = S.alv + ci * Cc;
  const float* etc_ = S.etv + ci * Cc;
  float beta[Cc], wb[Cc], ce[Cc], E[Cc], T[Cc];
  for (int i = 0; i < Cc; ++i) beta[i] = 1.f - alc[i];
  wb[Cc - 1] = 1.f;
  for (int m = Cc - 2; m >= 0; --m) wb[m] = wb[m + 1] * beta[m + 1];
  float bc_last = wb[0] * beta[0];
  float p = 1.f, A = 0.f;
  for (int m = 0; m < Cc; ++m) { p *= etc_[m]; ce[m] = p; A += wb[m] * ce[m]; }
  E[Cc - 1] = 1.f; T[Cc - 1] = 1.f;
  for (int n = Cc - 2; n >= 0; --n) {
    E[n] = E[n + 1] * etc_[n + 1];
    T[n] = wb[n] + etc_[n + 1] * T[n + 1];
  }
  for (int b = 0; b < Bb; ++b)
    for (int t = 0; t < Cc; ++t) {
      S.wBv[ci * RowsC + b * Cc + t] = T[t];
      S.wEv[ci * RowsC + b * Cc + t] = E[t];
    }
  S.scal[ci * 4 + 0] = bc_last; S.scal[ci * 4 + 1] = A; S.scal[ci * 4 + 2] = ce[Cc - 1];
}

// 128x128-tile GEMM (2-phase dbuf) for retrieval
template<int EPI>
__global__ __launch_bounds__(256) void mgemm128_k(
    const u16* __restrict__ A, const u16* __restrict__ Bt,
    float* C0, u16* Cb, int M, int N, int K)
{
  constexpr int TS = 128, BK = 64;
  constexpr int BUF = TS * BK;
  __shared__ __align__(16) u16 As[2 * BUF];
  __shared__ __align__(16) u16 Bs[2 * BUF];
  const int tid = threadIdx.x;
  const int l = tid & 63, lr = l & 15, lq = l >> 4;
  const int w = tid >> 6, wr = w >> 1, wc = w & 1;
  const int bm = blockIdx.y * TS, bn = blockIdx.x * TS;

  f32x4 acc[4][4];
  #pragma unroll
  for (int i = 0; i < 4; ++i)
    #pragma unroll
    for (int j = 0; j < 4; ++j) acc[i][j] = f32x4{0.f, 0.f, 0.f, 0.f};

  auto stage = [&](int k0, int buf) {
    u16* dA = As + buf * BUF;
    u16* dB = Bs + buf * BUF;
    #pragma unroll
    for (int i = 0; i < 4; ++i) {
      int e = i * 256 + tid;
      int r = e >> 3, c = (e & 7) ^ (r & 7);
      llds16(A  + (size_t)(bm + r) * K + k0 + c * 8, dA + e * 8);
      llds16(Bt + (size_t)(bn + r) * K + k0 + c * 8, dB + e * 8);
    }
  };

  stage(0, 0);
  drain_barrier();
  const int nt = K / BK;
  int cur = 0;
  for (int t = 0; t < nt; ++t) {
    if (t + 1 < nt) stage((t + 1) * BK, cur ^ 1);
    const u16* sA = As + cur * BUF;
    const u16* sB = Bs + cur * BUF;
    #pragma unroll
    for (int kk = 0; kk < 2; ++kk) {
      bf16x8 av[4], bv[4];
      #pragma unroll
      for (int m = 0; m < 4; ++m) {
        int r = wr * 64 + m * 16 + lr;
        int c = (kk * 4 + lq) ^ (r & 7);
        av[m] = *reinterpret_cast<const bf16x8*>(&sA[r * BK + c * 8]);
      }
      #pragma unroll
      for (int n = 0; n < 4; ++n) {
        int r = wc * 64 + n * 16 + lr;
        int c = (kk * 4 + lq) ^ (r & 7);
        bv[n] = *reinterpret_cast<const bf16x8*>(&sB[r * BK + c * 8]);
      }
      #pragma unroll
      for (int m = 0; m < 4; ++m)
        #pragma unroll
        for (int n = 0; n < 4; ++n)
          acc[m][n] = __builtin_amdgcn_mfma_f32_16x16x32_bf16(av[m], bv[n], acc[m][n], 0, 0, 0);
    }
    drain_barrier();
    cur ^= 1;
  }

  #pragma unroll
  for (int m = 0; m < 4; ++m) {
    int gr0 = bm + wr * 64 + m * 16 + lq * 4;
    #pragma unroll
    for (int n = 0; n < 4; ++n) {
      int gc = bn + wc * 64 + n * 16 + lr;
      #pragma unroll
      for (int q = 0; q < 4; ++q) {
        size_t idx = (size_t)(gr0 + q) * N + gc;
        float v = acc[m][n][q];
        if (EPI == 0) C0[idx] = v;
        else          Cb[idx] = f2bf(siluf_(v));
      }
    }
  }
}

// init: prep (blk 0-511) + w1^T (blk 512-639) + converts (blk 640-1151)
__global__ __launch_bounds__(256) void init_k(
    const float* __restrict__ x,
    const float* __restrict__ aw, const float* __restrict__ ab,
    const float* __restrict__ tw, const float* __restrict__ tb,
    const float* __restrict__ ew, const float* __restrict__ eb,
    const float* __restrict__ wq, const float* __restrict__ wkw,
    const float* __restrict__ wvw, const float* __restrict__ mw0,
    const float* __restrict__ mw1, const float* __restrict__ mln,
    char* ws)
{
  WS S = mkws(ws);
  const int tid = threadIdx.x;
  if (blockIdx.x < 512) {
    __shared__ float red[256];
    int s = blockIdx.x;
    int ci = s >> 6, t = s & 63;
    float sa = 0.f, st = 0.f, se = 0.f;
    for (int b = 0; b < Bb; ++b) {
      const float* xr = x + ((size_t)b * Ss + s) * Dd;
      u16* dst = S.xcb + ((size_t)(ci * RowsC + b * Cc + t)) * Dd;
      for (int d = tid; d < Dd; d += 256) {
        float v = xr[d];
        dst[d] = f2bf(v);
        sa += v * aw[d]; st += v * tw[d]; se += v * ew[d];
      }
    }
    sa = block_reduce_sum(sa, red);
    st = block_reduce_sum(st, red);
    se = block_reduce_sum(se, red);
    if (tid == 0) {
      S.alv[s] = sigmoidf_(sa + Bb * ab[0]);
      S.thv[s] = sigmoidf_(st + Bb * tb[0]) * 0.01f;
      S.etv[s] = sigmoidf_(se + Bb * eb[0]);
    }
    return;
  }
  if (blockIdx.x < 640) {
    __shared__ float t[64][65];
    int tt = blockIdx.x - 512;
    int br = (tt & 7) * 64, bc = (tt >> 3) * 64;
    #pragma unroll
    for (int i = 0; i < 16; ++i) {
      int e = tid + i * 256;
      int r = e >> 6, c = e & 63;
      t[r][c] = mw1[(size_t)(br + r) * Ii + bc + c];
    }
    __syncthreads();
    #pragma unroll
    for (int i = 0; i < 16; ++i) {
      int e = tid + i * 256;
      int rr = e >> 6, cc = e & 63;
      S.w1tb[(size_t)(bc + rr) * Dd + br + cc] = f2bf(t[cc][rr]);
    }
    return;
  }
  const int i0 = (blockIdx.x - 640) * 256 + tid;
  const int stride = 512 * 256;
  for (int i = i0; i < (Dd * Dd) / 4; i += stride) {
    float4 v = ((const float4*)wkw)[i];
    ushort4 o; o.x = f2bf(v.x); o.y = f2bf(v.y); o.z = f2bf(v.z); o.w = f2bf(v.w);
    ((ushort4*)S.wkvqb)[i] = o;
    v = ((const float4*)wvw)[i];
    o.x = f2bf(v.x); o.y = f2bf(v.y); o.z = f2bf(v.z); o.w = f2bf(v.w);
    ((ushort4*)S.wkvqb)[i + (Dd * Dd) / 4] = o;
    v = ((const float4*)wq)[i];
    o.x = f2bf(v.x); o.y = f2bf(v.y); o.z = f2bf(v.z); o.w = f2bf(v.w);
    ((ushort4*)S.wkvqb)[i + (Dd * Dd) / 2] = o;
  }
  for (int i = i0; i < (Ii * Dd) / 4; i += stride) {
    float4 z4; z4.x = z4.y = z4.z = z4.w = 0.f;
    float4 v = ((const float4*)mw0)[i];
    ((float4*)S.w0c)[i] = v; ((float4*)S.Sw0)[i] = z4;
    ushort4 o; o.x = f2bf(v.x); o.y = f2bf(v.y); o.z = f2bf(v.z); o.w = f2bf(v.w);
    ((ushort4*)S.w0b)[i] = o;
    v = ((const float4*)mw1)[i];
    ((float4*)S.w1c)[i] = v; ((float4*)S.Sw1)[i] = z4;
    o.x = f2bf(v.x); o.y = f2bf(v.y); o.z = f2bf(v.z); o.w = f2bf(v.w);
    ((ushort4*)S.w1b)[i] = o;
  }
  for (int i = i0; i < Dd; i += stride) { S.lnc[i] = mln[i]; S.Sln[i] = 0.f; }
}

// combined norms: blk 0-511 K rows (+KT), blk 512-1023 Q rows
__global__ __launch_bounds__(256) void norm2_k(
    const float* __restrict__ tmpK, const float* __restrict__ Yq,
    float* Krows, u16* Kb, u16* KT,
    float* Qb, u16* Qbb,
    const float* __restrict__ kn, const float* __restrict__ qn)
{
  __shared__ u16 lt[4][Dd];
  const int tid = threadIdx.x, w = tid >> 6, l = tid & 63;
  const bool isQ = blockIdx.x >= 512;
  const int r0 = (isQ ? (int)blockIdx.x - 512 : (int)blockIdx.x) * 4;
  const int row = r0 + w, d0 = l * 8;
  const float* in = (isQ ? Yq : tmpK) + (size_t)row * Dd + d0;
  const float* nw = (isQ ? qn : kn) + d0;
  float v[8];
  *(float4*)&v[0] = *(const float4*)in;
  *(float4*)&v[4] = *(const float4*)(in + 4);
  float ss = 0.f;
  #pragma unroll
  for (int j = 0; j < 8; ++j) { v[j] = siluf_(v[j]); ss += v[j] * v[j]; }
  ss = wave_sum(ss);
  float rr = rsqrtf(ss / (float)Dd + EPS);
  float nv[8];
  *(float4*)&nv[0] = *(const float4*)nw;
  *(float4*)&nv[4] = *(const float4*)(nw + 4);
  float y[8]; u16x8 pb;
  #pragma unroll
  for (int j = 0; j < 8; ++j) { y[j] = v[j] * rr * nv[j]; pb[j] = f2bf(y[j]); }
  float* outf = (isQ ? Qb : Krows) + (size_t)row * Dd + d0;
  u16* outb = (isQ ? Qbb : Kb) + (size_t)row * Dd + d0;
  *(float4*)outf       = *(float4*)&y[0];
  *(float4*)(outf + 4) = *(float4*)&y[4];
  *(u16x8*)outb = pb;
  if (!isQ) {
    int ci = r0 >> 8, rloc = r0 & 255;
    u16* KTc = KT + (size_t)ci * Dd * RowsC;
    #pragma unroll
    for (int j = 0; j < 8; ++j) lt[w][d0 + j] = pb[j];
    __syncthreads();
    for (int d = tid; d < Dd; d += 256) {
      ushort4 pk;
      pk.x = lt[0][d]; pk.y = lt[1][d]; pk.z = lt[2][d]; pk.w = lt[3][d];
      *reinterpret_cast<ushort4*>(&KTc[(size_t)d * RowsC + rloc]) = pk;
    }
  }
}

// wave-per-row loss backward (sums 16 split-K Y partials)
__global__ __launch_bounds__(256) void loss_back4_k(
    const float* __restrict__ Kr, const float* __restrict__ Vr,
    const float* __restrict__ Yp, const float* __restrict__ lnc,
    const float* __restrict__ th, const float* __restrict__ wB,
    const float* __restrict__ wE,
    u16* __restrict__ dYb, u16* __restrict__ dYtW, u16* __restrict__ dYtE,
    float* __restrict__ gyr)
{
  __shared__ u16 lw[4][Dd];
  __shared__ u16 le[4][Dd];
  const int tid = threadIdx.x, w = tid >> 6, l = tid & 63;
  const int row = blockIdx.x * 4 + w, t = row & 63, d0 = l * 8;
  size_t base = (size_t)row * Dd + d0;

  float y[8] = {0.f, 0.f, 0.f, 0.f, 0.f, 0.f, 0.f, 0.f};
  #pragma unroll
  for (int p2 = 0; p2 < 16; ++p2) {
    const float* yp = Yp + (size_t)p2 * (RowsC * Dd) + base;
    float4 u0 = *(const float4*)yp;
    float4 u1 = *(const float4*)(yp + 4);
    y[0] += u0.x; y[1] += u0.y; y[2] += u0.z; y[3] += u0.w;
    y[4] += u1.x; y[5] += u1.y; y[6] += u1.z; y[7] += u1.w;
  }

  float kk[8], vv[8], lv[8];
  *(float4*)&kk[0] = *(const float4*)(Kr + base);
  *(float4*)&kk[4] = *(const float4*)(Kr + base + 4);
  *(float4*)&vv[0] = *(const float4*)(Vr + base);
  *(float4*)&vv[4] = *(const float4*)(Vr + base + 4);
  *(float4*)&lv[0] = *(const float4*)(lnc + d0);
  *(float4*)&lv[4] = *(const float4*)(lnc + d0 + 4);

  float ss = 0.f;
  #pragma unroll
  for (int q = 0; q < 8; ++q) ss += y[q] * y[q];
  ss = wave_sum(ss);
  float rr = rsqrtf(ss / (float)Dd + EPS);
  float c = 2.f * th[t] / (float)Dd;

  float g[8], s2 = 0.f;
  #pragma unroll
  for (int q = 0; q < 8; ++q) {
    g[q] = c * ((kk[q] + y[q] * rr * lv[q]) - vv[q]);
    s2 += g[q] * lv[q] * y[q];
  }
  s2 = wave_sum(s2);
  float coef = rr * rr * rr * s2 / (float)Dd;

  float wb = wB[row], we = wE[row];
  u16x8 pb; float gy[8];
  #pragma unroll
  for (int q = 0; q < 8; ++q) {
    float dv = rr * g[q] * lv[q] - coef * y[q];
    pb[q] = f2bf(dv);
    lw[w][d0 + q] = f2bf(dv * wb);
    le[w][d0 + q] = f2bf(dv * we);
    gy[q] = g[q] * y[q] * rr;
  }
  *(u16x8*)(dYb + base) = pb;
  *(float4*)(gyr + base)     = *(float4*)&gy[0];
  *(float4*)(gyr + base + 4) = *(float4*)&gy[4];

  __syncthreads();
  int r0 = blockIdx.x * 4;
  for (int d = tid; d < Dd; d += 256) {
    ushort4 pw, pe;
    pw.x = lw[0][d]; pw.y = lw[1][d]; pw.z = lw[2][d]; pw.w = lw[3][d];
    pe.x = le[0][d]; pe.y = le[1][d]; pe.z = le[2][d]; pe.w = le[3][d];
    *reinterpret_cast<ushort4*>(&dYtW[(size_t)d * RowsC + r0]) = pw;
    *reinterpret_cast<ushort4*>(&dYtE[(size_t)d * RowsC + r0]) = pe;
  }
}

// out[orig] = q + rms(y)*ln  (wave per row, permute back)
__global__ __launch_bounds__(256) void final4_k(
    const float* __restrict__ Q, const float* __restrict__ Y,
    const float* __restrict__ lnc, float* __restrict__ out)
{
  const int tid = threadIdx.x, w = tid >> 6, l = tid & 63;
  const int row = blockIdx.x * 4 + w;
  const int ci = row >> 8, wi = row & 255, b = wi >> 6, t = wi & 63;
  const int d0 = l * 8;
  const float* yr = Y + (size_t)row * Dd + d0;
  float y[8];
  *(float4*)&y[0] = *(const float4*)yr;
  *(float4*)&y[4] = *(const float4*)(yr + 4);
  float ss = 0.f;
  #pragma unroll
  for (int q = 0; q < 8; ++q) ss += y[q] * y[q];
  ss = wave_sum(ss);
  float rr = rsqrtf(ss / (float)Dd + EPS);
  const float* qb = Q + (size_t)row * Dd + d0;
  const float* lf = lnc + d0;
  float o[8];
  #pragma unroll
  for (int q = 0; q < 8; ++q) o[q] = qb[q] + y[q] * rr * lf[q];
  float* ob = out + ((size_t)b * Ss + ci * Cc + t) * Dd + d0;
  *(float4*)ob       = *(float4*)&o[0];
  *(float4*)(ob + 4) = *(float4*)&o[4];
}

} // namespace

extern "C" void kernel_launch(void* const* d_in, const int* in_sizes, int n_in,
                              void* d_out, int out_size, void* d_ws, size_t ws_size,
                              hipStream_t stream)
{
  const float* x   = (const float*)d_in[0];
  const float* wq  = (const float*)d_in[1];
  const float* wkw = (const float*)d_in[2];
  const float* wvw = (const float*)d_in[3];
  const float* qn  = (const float*)d_in[4];
  const float* kn  = (const float*)d_in[5];
  const float* aw  = (const float*)d_in[6];
  const float* ab  = (const float*)d_in[7];
  const float* tw  = (const float*)d_in[8];
  const float* tb  = (const float*)d_in[9];
  const float* ew  = (const float*)d_in[10];
  const float* eb  = (const float*)d_in[11];
  const float* mw0 = (const float*)d_in[12];
  const float* mw1 = (const float*)d_in[13];
  const float* mln = (const float*)d_in[14];
  float* out = (float*)d_out;
  char* ws = (char*)d_ws;
  WS S = mkws(ws);

  // ---- init (prep + transpose + converts), then gate scans inside kvq ----
  init_k<<<1152, 256, 0, stream>>>(x, aw, ab, tw, tb, ew, eb,
                                   wq, wkw, wvw, mw0, mw1, mln, ws);
  kvq_k<<<776, 256, 0, stream>>>(S.xcb, S.wkvqb, S.tmpK, S.Vrows, S.Yr, ws);
  norm2_k<<<1024, 256, 0, stream>>>(S.tmpK, S.Yr, S.Krows, S.Kb, S.KT,
                                    S.Qb, S.Qbb, kn, qn);

  // ---- sequential chunk loop: 4 launches per chunk ----
  for (int ci = 0; ci < nCk; ++ci) {
    const int p = ci & 1;
    const u16* Kbc = S.Kb + (size_t)ci * RowsC * Dd;
    const u16* KTc = S.KT + (size_t)ci * Dd * RowsC;
    const float* Krc = S.Krows + (size_t)ci * RowsC * Dd;
    const float* Vrc = S.Vrows + (size_t)ci * RowsC * Dd;
    const float* scc = S.scal + ci * 4;
    const float* wBc = S.wBv + ci * RowsC;
    const float* wEc = S.wEv + ci * RowsC;
    const float* thc = S.thv + ci * Cc;
    u16* w1b_cur = S.w1b + (size_t)p * Dd * Ii;
    u16* w1b_new = S.w1b + (size_t)(p ^ 1) * Dd * Ii;
    u16* w1t_cur = S.w1tb + (size_t)p * Ii * Dd;
    u16* w1t_new = S.w1tb + (size_t)(p ^ 1) * Ii * Dd;

    z0y_k<<<dim3(16, 4), 256, 0, stream>>>(
        Kbc, S.w0b, w1b_cur, S.Ht, S.dZb, S.Yp);
    loss_back4_k<<<RowsC / 4, 256, 0, stream>>>(
        Krc, Vrc, S.Yp, S.lnc, thc, wBc, wEc, S.dYb, S.dYtW, S.dYtE, S.gyr);
    s4_k<<<194, 256, 0, stream>>>(
        S.dYb, w1t_cur, S.dZb, S.dHtW, S.dHtE, S.gyr, S.lnc, S.Sln,
        S.dYtW, S.dYtE, S.Ht, S.w1c, S.Sw1, w1b_new, w1t_new,
        wBc, wEc, scc);
    g2b_k<<<128, 256, 0, stream>>>(
        S.dHtW, S.dHtE, KTc, S.w0c, S.Sw0, S.w0b, scc);
  }

  // ---- retrieval through final memory (final w1 copy is slot 0) ----
  mgemm128_k<4><<<dim3(Ii / 128, RowsAll / 128), 256, 0, stream>>>(
      S.Qbb, S.w0b, nullptr, S.Hrb, RowsAll, Ii, Dd);
  mgemm128_k<0><<<dim3(Dd / 128, RowsAll / 128), 256, 0, stream>>>(
      S.Hrb, S.w1b, S.Yr, nullptr, RowsAll, Dd, Ii);
  final4_k<<<RowsAll / 4, 256, 0, stream>>>(S.Qb, S.Yr, S.lnc, out);
}

// Round 12
// 374.665 us; speedup vs baseline: 1.1015x; 1.0315x over previous
//
#include <hip/hip_runtime.h>
#include <math.h>

#define EPS 1e-6f

namespace {

typedef unsigned short u16;
typedef unsigned int u32;
typedef __bf16 bf16x8 __attribute__((ext_vector_type(8)));
typedef float f32x4 __attribute__((ext_vector_type(4)));
typedef u16 u16x8 __attribute__((ext_vector_type(8)));

constexpr int Bb = 4, Ss = 512, Dd = 512, Ii = 1024, Cc = 64;
constexpr int nCk = 8, RowsC = 256, RowsAll = 2048;

__device__ __forceinline__ float sigmoidf_(float x) { return 1.f / (1.f + expf(-x)); }
__device__ __forceinline__ float siluf_(float x)    { return x / (1.f + expf(-x)); }

__device__ __forceinline__ u16 f2bf(float f) {
  u32 u = __float_as_uint(f);
  u32 r = u + 0x7fffu + ((u >> 16) & 1u);
  return (u16)(r >> 16);
}
__device__ __forceinline__ float bf2f(u16 u) {
  return __uint_as_float(((u32)u) << 16);
}

__device__ __forceinline__ void llds16(const u16* g, u16* l) {
  __builtin_amdgcn_global_load_lds((__attribute__((address_space(1))) void*)g,
                                   (__attribute__((address_space(3))) void*)l,
                                   16, 0, 0);
}

__device__ __forceinline__ void drain_barrier() {
  asm volatile("s_waitcnt vmcnt(0)" ::: "memory");
  __builtin_amdgcn_s_barrier();
}

__device__ __forceinline__ float wave_sum(float v) {
  #pragma unroll
  for (int m = 32; m > 0; m >>= 1) v += __shfl_xor(v, m, 64);
  return v;
}

__device__ __forceinline__ float block_reduce_sum(float v, float* red) {
  int tid = threadIdx.x;
  red[tid] = v; __syncthreads();
  for (int s = 128; s > 0; s >>= 1) {
    if (tid < s) red[tid] += red[tid + s];
    __syncthreads();
  }
  float r = red[0]; __syncthreads();
  return r;
}

// ---------------- workspace carve ----------------
struct WS {
  float *w0c, *Sw0, *w1c, *Sw1, *lnc, *Sln, *gyr,
        *alv, *thv, *etv, *wBv, *wEv, *scal, *Qb, *Yr;
  u16 *xcb, *wkvqb, *w0b, *w1b, *w1tb, *Kb, *KT, *Ht, *dZb,
      *dYb, *dYtW, *dYtE, *dHtW, *dHtE, *Qbb, *Hrb,
      *tmpKb, *Vrb, *Yqb, *Ypb;
};
__host__ __device__ inline WS mkws(char* base) {
  WS s; char* p = base + 256;
#define CF(nm, n) s.nm = (float*)p; p += (size_t)(n) * 4;
#define CU(nm, n) s.nm = (u16*)p;   p += (size_t)(n) * 2;
  CF(w0c, Ii*Dd) CF(Sw0, Ii*Dd) CF(w1c, Dd*Ii) CF(Sw1, Dd*Ii)
  CF(lnc, Dd) CF(Sln, Dd) CF(gyr, RowsC*Dd)
  CF(alv, Ss) CF(thv, Ss) CF(etv, Ss) CF(wBv, nCk*RowsC) CF(wEv, nCk*RowsC) CF(scal, nCk*4)
  CF(Qb, (size_t)RowsAll*Dd) CF(Yr, (size_t)RowsAll*Dd)
  CU(xcb, (size_t)RowsAll*Dd) CU(wkvqb, (size_t)3*Dd*Dd)
  CU(w0b, (size_t)Ii*Dd) CU(w1b, (size_t)2*Dd*Ii) CU(w1tb, (size_t)2*Ii*Dd)
  CU(Kb, (size_t)RowsAll*Dd) CU(KT, (size_t)RowsAll*Dd)
  CU(Ht, RowsC*Ii) CU(dZb, RowsC*Ii)
  CU(dYb, RowsC*Dd) CU(dYtW, RowsC*Dd) CU(dYtE, RowsC*Dd)
  CU(dHtW, RowsC*Ii) CU(dHtE, RowsC*Ii)
  CU(Qbb, (size_t)RowsAll*Dd) CU(Hrb, (size_t)RowsAll*Ii)
  CU(tmpKb, (size_t)RowsAll*Dd) CU(Vrb, (size_t)RowsAll*Dd)
  CU(Yqb, (size_t)RowsAll*Dd) CU(Ypb, (size_t)16*RowsC*Dd)
#undef CF
#undef CU
  return s;
}

// ---------------- 64x64 MFMA tile, BK/NBUF-param ----------------
// EPI: 0 C0=v (fp32)
//      1 KVQ split (bf16 outputs, C0/C1/C2 are u16* cast to float*):
//        gc<512 -> bf(v) | gc<1024 -> bf(silu(v)) | else bf(v)
//      3 dh=v*bf2f(Zb): CbT=bf(dh*wB)^T, CbT2=bf(dh*wE)^T
template<int BK, int NBUF, int EPI>
__device__ void tile64(
    u16* smA, u16* smB,
    const u16* __restrict__ A, const u16* __restrict__ Bt,
    int K, int N, int bm, int bn,
    float* C0, float* C1, float* C2,
    u16* CbT, u16* CbT2,
    const u16* Zb, const float* wB, const float* wE, int trM)
{
  constexpr int CPR = BK / 8;
  constexpr int NISS = (64 * CPR) / 256;
  constexpr int BUF = 64 * BK;
  const int tid = threadIdx.x;
  const int l = tid & 63, lr = l & 15, lq = l >> 4;
  const int w = tid >> 6, wr = w >> 1, wc = w & 1;

  f32x4 acc[2][2];
  #pragma unroll
  for (int i = 0; i < 2; ++i)
    #pragma unroll
    for (int j = 0; j < 2; ++j) acc[i][j] = f32x4{0.f, 0.f, 0.f, 0.f};

  auto stage = [&](int k0, int buf) {
    u16* dA = smA + buf * BUF;
    u16* dB = smB + buf * BUF;
    #pragma unroll
    for (int i = 0; i < NISS; ++i) {
      int e = i * 256 + tid;
      int r = e / CPR, c = (e & (CPR - 1)) ^ (r & (CPR - 1));
      llds16(A  + (size_t)(bm + r) * K + k0 + c * 8, dA + e * 8);
      llds16(Bt + (size_t)(bn + r) * K + k0 + c * 8, dB + e * 8);
    }
  };

  stage(0, 0);
  drain_barrier();
  const int nt = K / BK;
  int cur = 0;
  for (int t = 0; t < nt; ++t) {
    if (t + 1 < nt) stage((t + 1) * BK, (cur ^ 1) & (NBUF - 1));
    const u16* sA = smA + cur * BUF;
    const u16* sB = smB + cur * BUF;
    #pragma unroll
    for (int kk = 0; kk < BK / 32; ++kk) {
      bf16x8 av[2], bv[2];
      #pragma unroll
      for (int m = 0; m < 2; ++m) {
        int r = wr * 32 + m * 16 + lr;
        int c = (kk * 4 + lq) ^ (r & (CPR - 1));
        av[m] = *reinterpret_cast<const bf16x8*>(&sA[r * BK + c * 8]);
      }
      #pragma unroll
      for (int n = 0; n < 2; ++n) {
        int r = wc * 32 + n * 16 + lr;
        int c = (kk * 4 + lq) ^ (r & (CPR - 1));
        bv[n] = *reinterpret_cast<const bf16x8*>(&sB[r * BK + c * 8]);
      }
      #pragma unroll
      for (int m = 0; m < 2; ++m)
        #pragma unroll
        for (int n = 0; n < 2; ++n)
          acc[m][n] = __builtin_amdgcn_mfma_f32_16x16x32_bf16(av[m], bv[n], acc[m][n], 0, 0, 0);
    }
    drain_barrier();
    cur = (cur ^ 1) & (NBUF - 1);
  }

  #pragma unroll
  for (int m = 0; m < 2; ++m) {
    int gr0 = bm + wr * 32 + m * 16 + lq * 4;
    float wbq[4], weq[4];
    if (EPI == 3) {
      #pragma unroll
      for (int q = 0; q < 4; ++q) { wbq[q] = wB[gr0 + q]; weq[q] = wE[gr0 + q]; }
    }
    #pragma unroll
    for (int n = 0; n < 2; ++n) {
      int gc = bn + wc * 32 + n * 16 + lr;
      ushort4 t1, t2;
      #pragma unroll
      for (int q = 0; q < 4; ++q) {
        float v = acc[m][n][q];
        size_t idx = (size_t)(gr0 + q) * N + gc;
        if (EPI == 0) {
          C0[idx] = v;
        } else if (EPI == 1) {
          size_t rb = (size_t)(gr0 + q) * Dd;
          if (gc < Dd)            ((u16*)C0)[rb + gc] = f2bf(v);
          else if (gc < 2 * Dd)   ((u16*)C1)[rb + gc - Dd] = f2bf(siluf_(v));
          else                    ((u16*)C2)[rb + gc - 2 * Dd] = f2bf(v);
        } else if (EPI == 3) {
          float dh = v * bf2f(Zb[idx]);
          ((u16*)&t1)[q] = f2bf(dh * wbq[q]);
          ((u16*)&t2)[q] = f2bf(dh * weq[q]);
        }
      }
      if (EPI == 3) {
        *reinterpret_cast<ushort4*>(&CbT[(size_t)gc * trM + gr0]) = t1;
        *reinterpret_cast<ushort4*>(&CbT2[(size_t)gc * trM + gr0]) = t2;
      }
    }
  }
}

// ------------- dual-weighted grad tile + fused param update -----------
template<int BK, int NBUF, bool TR>
__device__ void gtile64(
    u16* smA, u16* smB, u16* smE,
    const u16* __restrict__ AW, const u16* __restrict__ AE,
    const u16* __restrict__ Bt,
    float* P, float* Sm, u16* Pb, u16* PbT, const float* scal,
    int M, int N, int K, int bm, int bn)
{
  constexpr int CPR = BK / 8;
  constexpr int NISS = (64 * CPR) / 256;
  constexpr int BUF = 64 * BK;
  const int tid = threadIdx.x;
  const int l = tid & 63, lr = l & 15, lq = l >> 4;
  const int w = tid >> 6, wr = w >> 1, wc = w & 1;

  f32x4 aM[2][2], aE[2][2];
  #pragma unroll
  for (int i = 0; i < 2; ++i)
    #pragma unroll
    for (int j = 0; j < 2; ++j) {
      aM[i][j] = f32x4{0.f, 0.f, 0.f, 0.f};
      aE[i][j] = f32x4{0.f, 0.f, 0.f, 0.f};
    }

  auto stage = [&](int k0, int buf) {
    u16* dA = smA + buf * BUF;
    u16* dE = smE + buf * BUF;
    u16* dB = smB + buf * BUF;
    #pragma unroll
    for (int i = 0; i < NISS; ++i) {
      int e = i * 256 + tid;
      int r = e / CPR, c = (e & (CPR - 1)) ^ (r & (CPR - 1));
      llds16(AW + (size_t)(bm + r) * K + k0 + c * 8, dA + e * 8);
      llds16(AE + (size_t)(bm + r) * K + k0 + c * 8, dE + e * 8);
      llds16(Bt + (size_t)(bn + r) * K + k0 + c * 8, dB + e * 8);
    }
  };

  stage(0, 0);
  drain_barrier();
  const int nt = K / BK;
  int cur = 0;
  for (int t = 0; t < nt; ++t) {
    if (t + 1 < nt) stage((t + 1) * BK, (cur ^ 1) & (NBUF - 1));
    const u16* sA = smA + cur * BUF;
    const u16* sE = smE + cur * BUF;
    const u16* sB = smB + cur * BUF;
    #pragma unroll
    for (int kk = 0; kk < BK / 32; ++kk) {
      bf16x8 awv[2], aev[2], bv[2];
      #pragma unroll
      for (int m = 0; m < 2; ++m) {
        int r = wr * 32 + m * 16 + lr;
        int c = (kk * 4 + lq) ^ (r & (CPR - 1));
        awv[m] = *reinterpret_cast<const bf16x8*>(&sA[r * BK + c * 8]);
        aev[m] = *reinterpret_cast<const bf16x8*>(&sE[r * BK + c * 8]);
      }
      #pragma unroll
      for (int n = 0; n < 2; ++n) {
        int r = wc * 32 + n * 16 + lr;
        int c = (kk * 4 + lq) ^ (r & (CPR - 1));
        bv[n] = *reinterpret_cast<const bf16x8*>(&sB[r * BK + c * 8]);
      }
      #pragma unroll
      for (int m = 0; m < 2; ++m)
        #pragma unroll
        for (int n = 0; n < 2; ++n) {
          aM[m][n] = __builtin_amdgcn_mfma_f32_16x16x32_bf16(awv[m], bv[n], aM[m][n], 0, 0, 0);
          aE[m][n] = __builtin_amdgcn_mfma_f32_16x16x32_bf16(aev[m], bv[n], aE[m][n], 0, 0, 0);
        }
    }
    drain_barrier();
    cur = (cur ^ 1) & (NBUF - 1);
  }

  float s0 = scal[0], s1 = scal[1], s2 = scal[2];
  #pragma unroll
  for (int m = 0; m < 2; ++m) {
    int gr0 = bm + wr * 32 + m * 16 + lq * 4;
    #pragma unroll
    for (int n = 0; n < 2; ++n) {
      int gc = bn + wc * 32 + n * 16 + lr;
      ushort4 t1;
      #pragma unroll
      for (int q = 0; q < 4; ++q) {
        size_t idx = (size_t)(gr0 + q) * N + gc;
        float p = P[idx], s = Sm[idx];
        float np = s0 * p + s1 * s - aM[m][n][q];
        float ns = s2 * s - aE[m][n][q];
        P[idx] = np; Sm[idx] = ns;
        Pb[idx] = f2bf(np);
        if (TR) ((u16*)&t1)[q] = f2bf(np);
      }
      if (TR) *reinterpret_cast<ushort4*>(&PbT[(size_t)gc * M + gr0]) = t1;
    }
  }
}

// ---------------- kernels ----------------

// Fused Z0 + split-K partial Y (Yp partials in bf16).
__global__ __launch_bounds__(256) void z0y_k(
    const u16* __restrict__ Kbc, const u16* __restrict__ w0b,
    const u16* __restrict__ w1b,
    u16* __restrict__ Ht, u16* __restrict__ dZb, u16* __restrict__ Ypb)
{
  __shared__ __align__(16) u16 sm[4 * 64 * 128 + 64 * 64];  // 72 KB
  u16* Hs = sm + 4 * 64 * 128;
  const int tid = threadIdx.x;
  const int l = tid & 63, lr = l & 15, lq = l >> 4;
  const int w = tid >> 6, wr = w >> 1, wc = w & 1;
  const int tj = blockIdx.x, tr = blockIdx.y;
  const int bm = tr * 64, bn = tj * 64;

  {
    constexpr int BK = 128, CPR = 16, NISS = 4, BUF = 64 * BK;
    u16* smA = sm; u16* smB = sm + 2 * BUF;
    f32x4 acc[2][2];
    #pragma unroll
    for (int i = 0; i < 2; ++i)
      #pragma unroll
      for (int j = 0; j < 2; ++j) acc[i][j] = f32x4{0.f, 0.f, 0.f, 0.f};

    auto stage = [&](int k0, int buf) {
      u16* dA = smA + buf * BUF;
      u16* dB = smB + buf * BUF;
      #pragma unroll
      for (int i = 0; i < NISS; ++i) {
        int e = i * 256 + tid;
        int r = e / CPR, c = (e & (CPR - 1)) ^ (r & (CPR - 1));
        llds16(Kbc + (size_t)(bm + r) * Dd + k0 + c * 8, dA + e * 8);
        llds16(w0b + (size_t)(bn + r) * Dd + k0 + c * 8, dB + e * 8);
      }
    };
    stage(0, 0);
    drain_barrier();
    int cur = 0;
    for (int t = 0; t < 4; ++t) {
      if (t + 1 < 4) stage((t + 1) * BK, cur ^ 1);
      const u16* sA = smA + cur * BUF;
      const u16* sB = smB + cur * BUF;
      #pragma unroll
      for (int kk = 0; kk < 4; ++kk) {
        bf16x8 av[2], bv[2];
        #pragma unroll
        for (int m = 0; m < 2; ++m) {
          int r = wr * 32 + m * 16 + lr;
          int c = (kk * 4 + lq) ^ (r & (CPR - 1));
          av[m] = *reinterpret_cast<const bf16x8*>(&sA[r * BK + c * 8]);
        }
        #pragma unroll
        for (int n = 0; n < 2; ++n) {
          int r = wc * 32 + n * 16 + lr;
          int c = (kk * 4 + lq) ^ (r & (CPR - 1));
          bv[n] = *reinterpret_cast<const bf16x8*>(&sB[r * BK + c * 8]);
        }
        #pragma unroll
        for (int m = 0; m < 2; ++m)
          #pragma unroll
          for (int n = 0; n < 2; ++n)
            acc[m][n] = __builtin_amdgcn_mfma_f32_16x16x32_bf16(av[m], bv[n], acc[m][n], 0, 0, 0);
      }
      drain_barrier();
      cur ^= 1;
    }

    #pragma unroll
    for (int i = 0; i < 16; ++i) {
      int e = i * 256 + tid;
      int r = e >> 3, c = (e & 7) ^ (r & 7);
      llds16(w1b + (size_t)r * Ii + bn + c * 8, sm + e * 8);
    }

    #pragma unroll
    for (int m = 0; m < 2; ++m) {
      int gr0 = bm + wr * 32 + m * 16 + lq * 4;
      int rl0 = wr * 32 + m * 16 + lq * 4;
      #pragma unroll
      for (int n = 0; n < 2; ++n) {
        int gc = bn + wc * 32 + n * 16 + lr;
        int cl = wc * 32 + n * 16 + lr;
        ushort4 t1;
        #pragma unroll
        for (int q = 0; q < 4; ++q) {
          float v = acc[m][n][q];
          float sg = 1.f / (1.f + expf(-v));
          float h = v * sg;
          float ds = sg * (1.f + v * (1.f - sg));
          u16 hb = f2bf(h);
          ((u16*)&t1)[q] = hb;
          dZb[(size_t)(gr0 + q) * Ii + gc] = f2bf(ds);
          int rl = rl0 + q;
          Hs[rl * 64 + ((((cl >> 3) ^ (rl & 7)) << 3) | (cl & 7))] = hb;
        }
        *reinterpret_cast<ushort4*>(&Ht[(size_t)gc * RowsC + gr0]) = t1;
      }
    }
  }

  asm volatile("s_waitcnt vmcnt(0)" ::: "memory");
  __syncthreads();

  {
    f32x4 yacc[2][16];
    #pragma unroll
    for (int m = 0; m < 2; ++m)
      #pragma unroll
      for (int n = 0; n < 16; ++n) yacc[m][n] = f32x4{0.f, 0.f, 0.f, 0.f};

    #pragma unroll
    for (int kk = 0; kk < 2; ++kk) {
      bf16x8 av[2];
      #pragma unroll
      for (int m = 0; m < 2; ++m) {
        int r = wr * 32 + m * 16 + lr;
        int c = (kk * 4 + lq) ^ (r & 7);
        av[m] = *reinterpret_cast<const bf16x8*>(&Hs[r * 64 + c * 8]);
      }
      #pragma unroll
      for (int n = 0; n < 16; ++n) {
        int r = wc * 256 + n * 16 + lr;
        int c = (kk * 4 + lq) ^ (r & 7);
        bf16x8 bv = *reinterpret_cast<const bf16x8*>(&sm[r * 64 + c * 8]);
        #pragma unroll
        for (int m = 0; m < 2; ++m)
          yacc[m][n] = __builtin_amdgcn_mfma_f32_16x16x32_bf16(av[m], bv, yacc[m][n], 0, 0, 0);
      }
    }

    u16* Yo = Ypb + (size_t)tj * RowsC * Dd;
    #pragma unroll
    for (int m = 0; m < 2; ++m) {
      int gr0 = bm + wr * 32 + m * 16 + lq * 4;
      #pragma unroll
      for (int n = 0; n < 16; ++n) {
        int gc = wc * 256 + n * 16 + lr;
        #pragma unroll
        for (int q = 0; q < 4; ++q)
          Yo[(size_t)(gr0 + q) * Dd + gc] = f2bf(yacc[m][n][q]);
      }
    }
  }
}

// S4: dH GEMM (blk 0-63) + colsum/ln (blk 64-65) + w1 grad+update (blk 66-193)
__global__ __launch_bounds__(256) void s4_k(
    const u16* __restrict__ dYb, const u16* __restrict__ w1t_cur,
    const u16* __restrict__ dZb, u16* dHtW, u16* dHtE,
    const float* __restrict__ gyr, float* lnc, float* Sln,
    const u16* __restrict__ dYtW, const u16* __restrict__ dYtE,
    const u16* __restrict__ Ht,
    float* w1c, float* Sw1, u16* w1b_new, u16* w1t_new,
    const float* wB, const float* wE, const float* scal)
{
  __shared__ __align__(16) u16 sm[6 * 64 * 128];
  int j = blockIdx.x;
  if (j < 64) {
    int tm = j & 3, tn = j >> 2;
    tile64<128, 2, 3>(sm, sm + 2 * 64 * 128, dYb, w1t_cur, Dd, Ii,
                      tm * 64, tn * 64,
                      nullptr, nullptr, nullptr, dHtW, dHtE,
                      dZb, wB, wE, RowsC);
  } else if (j < 66) {
    int d = (j - 64) * 256 + threadIdx.x;
    float sm2 = 0.f, se2 = 0.f;
    for (int r = 0; r < RowsC; ++r) {
      float vv = gyr[(size_t)r * Dd + d];
      sm2 += wB[r] * vv; se2 += wE[r] * vv;
    }
    float pp = lnc[d], sn = Sln[d];
    lnc[d] = scal[0] * pp + scal[1] * sn - sm2;
    Sln[d] = scal[2] * sn - se2;
  } else {
    int q = j - 66;                       // 128 tiles: M=Dd(8) x N=Ii(16)
    gtile64<128, 2, true>(sm, sm + 2 * 64 * 128, sm + 4 * 64 * 128,
                          dYtW, dYtE, Ht, w1c, Sw1, w1b_new, w1t_new,
                          scal, Dd, Ii, RowsC, (q >> 4) * 64, (q & 15) * 64);
  }
}

// w0 grad + update [grid 128]
__global__ __launch_bounds__(256) void g2b_k(
    const u16* __restrict__ dHtW, const u16* __restrict__ dHtE,
    const u16* __restrict__ KTc,
    float* w0c, float* Sw0, u16* w0b, const float* scal)
{
  __shared__ __align__(16) u16 sm[6 * 64 * 128];
  int j = blockIdx.x;                     // M=Ii(16) x N=Dd(8)
  gtile64<128, 2, false>(sm, sm + 2 * 64 * 128, sm + 4 * 64 * 128,
                         dHtW, dHtE, KTc, w0c, Sw0, w0b, nullptr,
                         scal, Ii, Dd, RowsC, (j >> 3) * 64, (j & 7) * 64);
}

// KVQ GEMM (blk 0-767, bf16 outputs) + per-chunk gate scans (blk 768-775)
__global__ __launch_bounds__(256) void kvq_k(
    const u16* __restrict__ xcb, const u16* __restrict__ wkvqb,
    u16* tmpKb, u16* Vrb, u16* Yqb, char* ws)
{
  __shared__ __align__(16) u16 sm[4 * 64 * 128];
  int j = blockIdx.x;
  if (j < 768) {
    int tn = j % 24, tm = j / 24;
    tile64<128, 2, 1>(sm, sm + 2 * 64 * 128, xcb, wkvqb, Dd, 3 * Dd,
                      tm * 64, tn * 64,
                      (float*)tmpKb, (float*)Vrb, (float*)Yqb, nullptr, nullptr,
                      nullptr, nullptr, nullptr, 0);
    return;
  }
  if (threadIdx.x != 0) return;
  WS S = mkws(ws);
  int ci = j - 768;
  const float* alc = S.alv + ci * Cc;
  const float* etc_ = S.etv + ci * Cc;
  float beta[Cc], wb[Cc], ce[Cc], E[Cc], T[Cc];
  for (int i = 0; i < Cc; ++i) beta[i] = 1.f - alc[i];
  wb[Cc - 1] = 1.f;
  for (int m = Cc - 2; m >= 0; --m) wb[m] = wb[m + 1] * beta[m + 1];
  float bc_last = wb[0] * beta[0];
  float p = 1.f, A = 0.f;
  for (int m = 0; m < Cc; ++m) { p *= etc_[m]; ce[m] = p; A += wb[m] * ce[m]; }
  E[Cc - 1] = 1.f; T[Cc - 1] = 1.f;
  for (int n = Cc - 2; n >= 0; --n) {
    E[n] = E[n + 1] * etc_[n + 1];
    T[n] = wb[n] + etc_[n + 1] * T[n + 1];
  }
  for (int b = 0; b < Bb; ++b)
    for (int t = 0; t < Cc; ++t) {
      S.wBv[ci * RowsC + b * Cc + t] = T[t];
      S.wEv[ci * RowsC + b * Cc + t] = E[t];
    }
  S.scal[ci * 4 + 0] = bc_last; S.scal[ci * 4 + 1] = A; S.scal[ci * 4 + 2] = ce[Cc - 1];
}

// 128x128-tile GEMM (2-phase dbuf) for retrieval
template<int EPI>
__global__ __launch_bounds__(256) void mgemm128_k(
    const u16* __restrict__ A, const u16* __restrict__ Bt,
    float* C0, u16* Cb, int M, int N, int K)
{
  constexpr int TS = 128, BK = 64;
  constexpr int BUF = TS * BK;
  __shared__ __align__(16) u16 As[2 * BUF];
  __shared__ __align__(16) u16 Bs[2 * BUF];
  const int tid = threadIdx.x;
  const int l = tid & 63, lr = l & 15, lq = l >> 4;
  const int w = tid >> 6, wr = w >> 1, wc = w & 1;
  const int bm = blockIdx.y * TS, bn = blockIdx.x * TS;

  f32x4 acc[4][4];
  #pragma unroll
  for (int i = 0; i < 4; ++i)
    #pragma unroll
    for (int j = 0; j < 4; ++j) acc[i][j] = f32x4{0.f, 0.f, 0.f, 0.f};

  auto stage = [&](int k0, int buf) {
    u16* dA = As + buf * BUF;
    u16* dB = Bs + buf * BUF;
    #pragma unroll
    for (int i = 0; i < 4; ++i) {
      int e = i * 256 + tid;
      int r = e >> 3, c = (e & 7) ^ (r & 7);
      llds16(A  + (size_t)(bm + r) * K + k0 + c * 8, dA + e * 8);
      llds16(Bt + (size_t)(bn + r) * K + k0 + c * 8, dB + e * 8);
    }
  };

  stage(0, 0);
  drain_barrier();
  const int nt = K / BK;
  int cur = 0;
  for (int t = 0; t < nt; ++t) {
    if (t + 1 < nt) stage((t + 1) * BK, cur ^ 1);
    const u16* sA = As + cur * BUF;
    const u16* sB = Bs + cur * BUF;
    #pragma unroll
    for (int kk = 0; kk < 2; ++kk) {
      bf16x8 av[4], bv[4];
      #pragma unroll
      for (int m = 0; m < 4; ++m) {
        int r = wr * 64 + m * 16 + lr;
        int c = (kk * 4 + lq) ^ (r & 7);
        av[m] = *reinterpret_cast<const bf16x8*>(&sA[r * BK + c * 8]);
      }
      #pragma unroll
      for (int n = 0; n < 4; ++n) {
        int r = wc * 64 + n * 16 + lr;
        int c = (kk * 4 + lq) ^ (r & 7);
        bv[n] = *reinterpret_cast<const bf16x8*>(&sB[r * BK + c * 8]);
      }
      #pragma unroll
      for (int m = 0; m < 4; ++m)
        #pragma unroll
        for (int n = 0; n < 4; ++n)
          acc[m][n] = __builtin_amdgcn_mfma_f32_16x16x32_bf16(av[m], bv[n], acc[m][n], 0, 0, 0);
    }
    drain_barrier();
    cur ^= 1;
  }

  #pragma unroll
  for (int m = 0; m < 4; ++m) {
    int gr0 = bm + wr * 64 + m * 16 + lq * 4;
    #pragma unroll
    for (int n = 0; n < 4; ++n) {
      int gc = bn + wc * 64 + n * 16 + lr;
      #pragma unroll
      for (int q = 0; q < 4; ++q) {
        size_t idx = (size_t)(gr0 + q) * N + gc;
        float v = acc[m][n][q];
        if (EPI == 0) C0[idx] = v;
        else          Cb[idx] = f2bf(siluf_(v));
      }
    }
  }
}

// init: prep (blk 0-511) + w1^T (blk 512-639) + converts (blk 640-1151)
__global__ __launch_bounds__(256) void init_k(
    const float* __restrict__ x,
    const float* __restrict__ aw, const float* __restrict__ ab,
    const float* __restrict__ tw, const float* __restrict__ tb,
    const float* __restrict__ ew, const float* __restrict__ eb,
    const float* __restrict__ wq, const float* __restrict__ wkw,
    const float* __restrict__ wvw, const float* __restrict__ mw0,
    const float* __restrict__ mw1, const float* __restrict__ mln,
    char* ws)
{
  WS S = mkws(ws);
  const int tid = threadIdx.x;
  if (blockIdx.x < 512) {
    __shared__ float red[256];
    int s = blockIdx.x;
    int ci = s >> 6, t = s & 63;
    float sa = 0.f, st = 0.f, se = 0.f;
    for (int b = 0; b < Bb; ++b) {
      const float* xr = x + ((size_t)b * Ss + s) * Dd;
      u16* dst = S.xcb + ((size_t)(ci * RowsC + b * Cc + t)) * Dd;
      for (int d = tid; d < Dd; d += 256) {
        float v = xr[d];
        dst[d] = f2bf(v);
        sa += v * aw[d]; st += v * tw[d]; se += v * ew[d];
      }
    }
    sa = block_reduce_sum(sa, red);
    st = block_reduce_sum(st, red);
    se = block_reduce_sum(se, red);
    if (tid == 0) {
      S.alv[s] = sigmoidf_(sa + Bb * ab[0]);
      S.thv[s] = sigmoidf_(st + Bb * tb[0]) * 0.01f;
      S.etv[s] = sigmoidf_(se + Bb * eb[0]);
    }
    return;
  }
  if (blockIdx.x < 640) {
    __shared__ float t[64][65];
    int tt = blockIdx.x - 512;
    int br = (tt & 7) * 64, bc = (tt >> 3) * 64;
    #pragma unroll
    for (int i = 0; i < 16; ++i) {
      int e = tid + i * 256;
      int r = e >> 6, c = e & 63;
      t[r][c] = mw1[(size_t)(br + r) * Ii + bc + c];
    }
    __syncthreads();
    #pragma unroll
    for (int i = 0; i < 16; ++i) {
      int e = tid + i * 256;
      int rr = e >> 6, cc = e & 63;
      S.w1tb[(size_t)(bc + rr) * Dd + br + cc] = f2bf(t[cc][rr]);
    }
    return;
  }
  const int i0 = (blockIdx.x - 640) * 256 + tid;
  const int stride = 512 * 256;
  for (int i = i0; i < (Dd * Dd) / 4; i += stride) {
    float4 v = ((const float4*)wkw)[i];
    ushort4 o; o.x = f2bf(v.x); o.y = f2bf(v.y); o.z = f2bf(v.z); o.w = f2bf(v.w);
    ((ushort4*)S.wkvqb)[i] = o;
    v = ((const float4*)wvw)[i];
    o.x = f2bf(v.x); o.y = f2bf(v.y); o.z = f2bf(v.z); o.w = f2bf(v.w);
    ((ushort4*)S.wkvqb)[i + (Dd * Dd) / 4] = o;
    v = ((const float4*)wq)[i];
    o.x = f2bf(v.x); o.y = f2bf(v.y); o.z = f2bf(v.z); o.w = f2bf(v.w);
    ((ushort4*)S.wkvqb)[i + (Dd * Dd) / 2] = o;
  }
  for (int i = i0; i < (Ii * Dd) / 4; i += stride) {
    float4 z4; z4.x = z4.y = z4.z = z4.w = 0.f;
    float4 v = ((const float4*)mw0)[i];
    ((float4*)S.w0c)[i] = v; ((float4*)S.Sw0)[i] = z4;
    ushort4 o; o.x = f2bf(v.x); o.y = f2bf(v.y); o.z = f2bf(v.z); o.w = f2bf(v.w);
    ((ushort4*)S.w0b)[i] = o;
    v = ((const float4*)mw1)[i];
    ((float4*)S.w1c)[i] = v; ((float4*)S.Sw1)[i] = z4;
    o.x = f2bf(v.x); o.y = f2bf(v.y); o.z = f2bf(v.z); o.w = f2bf(v.w);
    ((ushort4*)S.w1b)[i] = o;
  }
  for (int i = i0; i < Dd; i += stride) { S.lnc[i] = mln[i]; S.Sln[i] = 0.f; }
}

// combined norms: blk 0-511 K rows (Kb bf16 + KT), blk 512-1023 Q rows
__global__ __launch_bounds__(256) void norm2_k(
    const u16* __restrict__ tmpKb, const u16* __restrict__ Yqb,
    u16* Kb, u16* KT, float* Qb, u16* Qbb,
    const float* __restrict__ kn, const float* __restrict__ qn)
{
  __shared__ u16 lt[4][Dd];
  const int tid = threadIdx.x, w = tid >> 6, l = tid & 63;
  const bool isQ = blockIdx.x >= 512;
  const int r0 = (isQ ? (int)blockIdx.x - 512 : (int)blockIdx.x) * 4;
  const int row = r0 + w, d0 = l * 8;
  const u16* in = (isQ ? Yqb : tmpKb) + (size_t)row * Dd + d0;
  const float* nw = (isQ ? qn : kn) + d0;
  u16x8 iu = *reinterpret_cast<const u16x8*>(in);
  float v[8];
  float ss = 0.f;
  #pragma unroll
  for (int j = 0; j < 8; ++j) { v[j] = siluf_(bf2f(iu[j])); ss += v[j] * v[j]; }
  ss = wave_sum(ss);
  float rr = rsqrtf(ss / (float)Dd + EPS);
  float nv[8];
  *(float4*)&nv[0] = *(const float4*)nw;
  *(float4*)&nv[4] = *(const float4*)(nw + 4);
  float y[8]; u16x8 pb;
  #pragma unroll
  for (int j = 0; j < 8; ++j) { y[j] = v[j] * rr * nv[j]; pb[j] = f2bf(y[j]); }
  if (isQ) {
    float* outf = Qb + (size_t)row * Dd + d0;
    *(float4*)outf       = *(float4*)&y[0];
    *(float4*)(outf + 4) = *(float4*)&y[4];
    *(u16x8*)(Qbb + (size_t)row * Dd + d0) = pb;
  } else {
    *(u16x8*)(Kb + (size_t)row * Dd + d0) = pb;
    int ci = r0 >> 8, rloc = r0 & 255;
    u16* KTc = KT + (size_t)ci * Dd * RowsC;
    #pragma unroll
    for (int j = 0; j < 8; ++j) lt[w][d0 + j] = pb[j];
    __syncthreads();
    for (int d = tid; d < Dd; d += 256) {
      ushort4 pk;
      pk.x = lt[0][d]; pk.y = lt[1][d]; pk.z = lt[2][d]; pk.w = lt[3][d];
      *reinterpret_cast<ushort4*>(&KTc[(size_t)d * RowsC + rloc]) = pk;
    }
  }
}

// wave-per-row loss backward (sums 16 bf16 split-K Y partials; bf16 K/V)
__global__ __launch_bounds__(256) void loss_back4_k(
    const u16* __restrict__ Kr, const u16* __restrict__ Vr,
    const u16* __restrict__ Ypb, const float* __restrict__ lnc,
    const float* __restrict__ th, const float* __restrict__ wB,
    const float* __restrict__ wE,
    u16* __restrict__ dYb, u16* __restrict__ dYtW, u16* __restrict__ dYtE,
    float* __restrict__ gyr)
{
  __shared__ u16 lw[4][Dd];
  __shared__ u16 le[4][Dd];
  const int tid = threadIdx.x, w = tid >> 6, l = tid & 63;
  const int row = blockIdx.x * 4 + w, t = row & 63, d0 = l * 8;
  size_t base = (size_t)row * Dd + d0;

  float y[8] = {0.f, 0.f, 0.f, 0.f, 0.f, 0.f, 0.f, 0.f};
  #pragma unroll
  for (int p2 = 0; p2 < 16; ++p2) {
    u16x8 u = *reinterpret_cast<const u16x8*>(Ypb + (size_t)p2 * (RowsC * Dd) + base);
    #pragma unroll
    for (int q = 0; q < 8; ++q) y[q] += bf2f(u[q]);
  }

  u16x8 ku = *reinterpret_cast<const u16x8*>(Kr + base);
  u16x8 vu = *reinterpret_cast<const u16x8*>(Vr + base);
  float kk[8], vv[8], lv[8];
  #pragma unroll
  for (int q = 0; q < 8; ++q) { kk[q] = bf2f(ku[q]); vv[q] = bf2f(vu[q]); }
  *(float4*)&lv[0] = *(const float4*)(lnc + d0);
  *(float4*)&lv[4] = *(const float4*)(lnc + d0 + 4);

  float ss = 0.f;
  #pragma unroll
  for (int q = 0; q < 8; ++q) ss += y[q] * y[q];
  ss = wave_sum(ss);
  float rr = rsqrtf(ss / (float)Dd + EPS);
  float c = 2.f * th[t] / (float)Dd;

  float g[8], s2 = 0.f;
  #pragma unroll
  for (int q = 0; q < 8; ++q) {
    g[q] = c * ((kk[q] + y[q] * rr * lv[q]) - vv[q]);
    s2 += g[q] * lv[q] * y[q];
  }
  s2 = wave_sum(s2);
  float coef = rr * rr * rr * s2 / (float)Dd;

  float wb = wB[row], we = wE[row];
  u16x8 pb; float gy[8];
  #pragma unroll
  for (int q = 0; q < 8; ++q) {
    float dv = rr * g[q] * lv[q] - coef * y[q];
    pb[q] = f2bf(dv);
    lw[w][d0 + q] = f2bf(dv * wb);
    le[w][d0 + q] = f2bf(dv * we);
    gy[q] = g[q] * y[q] * rr;
  }
  *(u16x8*)(dYb + base) = pb;
  *(float4*)(gyr + base)     = *(float4*)&gy[0];
  *(float4*)(gyr + base + 4) = *(float4*)&gy[4];

  __syncthreads();
  int r0 = blockIdx.x * 4;
  for (int d = tid; d < Dd; d += 256) {
    ushort4 pw, pe;
    pw.x = lw[0][d]; pw.y = lw[1][d]; pw.z = lw[2][d]; pw.w = lw[3][d];
    pe.x = le[0][d]; pe.y = le[1][d]; pe.z = le[2][d]; pe.w = le[3][d];
    *reinterpret_cast<ushort4*>(&dYtW[(size_t)d * RowsC + r0]) = pw;
    *reinterpret_cast<ushort4*>(&dYtE[(size_t)d * RowsC + r0]) = pe;
  }
}

// out[orig] = q + rms(y)*ln  (wave per row, permute back)
__global__ __launch_bounds__(256) void final4_k(
    const float* __restrict__ Q, const float* __restrict__ Y,
    const float* __restrict__ lnc, float* __restrict__ out)
{
  const int tid = threadIdx.x, w = tid >> 6, l = tid & 63;
  const int row = blockIdx.x * 4 + w;
  const int ci = row >> 8, wi = row & 255, b = wi >> 6, t = wi & 63;
  const int d0 = l * 8;
  const float* yr = Y + (size_t)row * Dd + d0;
  float y[8];
  *(float4*)&y[0] = *(const float4*)yr;
  *(float4*)&y[4] = *(const float4*)(yr + 4);
  float ss = 0.f;
  #pragma unroll
  for (int q = 0; q < 8; ++q) ss += y[q] * y[q];
  ss = wave_sum(ss);
  float rr = rsqrtf(ss / (float)Dd + EPS);
  const float* qb = Q + (size_t)row * Dd + d0;
  const float* lf = lnc + d0;
  float o[8];
  #pragma unroll
  for (int q = 0; q < 8; ++q) o[q] = qb[q] + y[q] * rr * lf[q];
  float* ob = out + ((size_t)b * Ss + ci * Cc + t) * Dd + d0;
  *(float4*)ob       = *(float4*)&o[0];
  *(float4*)(ob + 4) = *(float4*)&o[4];
}

} // namespace

extern "C" void kernel_launch(void* const* d_in, const int* in_sizes, int n_in,
                              void* d_out, int out_size, void* d_ws, size_t ws_size,
                              hipStream_t stream)
{
  const float* x   = (const float*)d_in[0];
  const float* wq  = (const float*)d_in[1];
  const float* wkw = (const float*)d_in[2];
  const float* wvw = (const float*)d_in[3];
  const float* qn  = (const float*)d_in[4];
  const float* kn  = (const float*)d_in[5];
  const float* aw  = (const float*)d_in[6];
  const float* ab  = (const float*)d_in[7];
  const float* tw  = (const float*)d_in[8];
  const float* tb  = (const float*)d_in[9];
  const float* ew  = (const float*)d_in[10];
  const float* eb  = (const float*)d_in[11];
  const float* mw0 = (const float*)d_in[12];
  const float* mw1 = (const float*)d_in[13];
  const float* mln = (const float*)d_in[14];
  float* out = (float*)d_out;
  char* ws = (char*)d_ws;
  WS S = mkws(ws);

  // ---- init (prep + transpose + converts), then gate scans inside kvq ----
  init_k<<<1152, 256, 0, stream>>>(x, aw, ab, tw, tb, ew, eb,
                                   wq, wkw, wvw, mw0, mw1, mln, ws);
  kvq_k<<<776, 256, 0, stream>>>(S.xcb, S.wkvqb, S.tmpKb, S.Vrb, S.Yqb, ws);
  norm2_k<<<1024, 256, 0, stream>>>(S.tmpKb, S.Yqb, S.Kb, S.KT,
                                    S.Qb, S.Qbb, kn, qn);

  // ---- sequential chunk loop: 4 launches per chunk ----
  for (int ci = 0; ci < nCk; ++ci) {
    const int p = ci & 1;
    const u16* Kbc = S.Kb + (size_t)ci * RowsC * Dd;
    const u16* KTc = S.KT + (size_t)ci * Dd * RowsC;
    const u16* Vrc = S.Vrb + (size_t)ci * RowsC * Dd;
    const float* scc = S.scal + ci * 4;
    const float* wBc = S.wBv + ci * RowsC;
    const float* wEc = S.wEv + ci * RowsC;
    const float* thc = S.thv + ci * Cc;
    u16* w1b_cur = S.w1b + (size_t)p * Dd * Ii;
    u16* w1b_new = S.w1b + (size_t)(p ^ 1) * Dd * Ii;
    u16* w1t_cur = S.w1tb + (size_t)p * Ii * Dd;
    u16* w1t_new = S.w1tb + (size_t)(p ^ 1) * Ii * Dd;

    z0y_k<<<dim3(16, 4), 256, 0, stream>>>(
        Kbc, S.w0b, w1b_cur, S.Ht, S.dZb, S.Ypb);
    loss_back4_k<<<RowsC / 4, 256, 0, stream>>>(
        Kbc, Vrc, S.Ypb, S.lnc, thc, wBc, wEc, S.dYb, S.dYtW, S.dYtE, S.gyr);
    s4_k<<<194, 256, 0, stream>>>(
        S.dYb, w1t_cur, S.dZb, S.dHtW, S.dHtE, S.gyr, S.lnc, S.Sln,
        S.dYtW, S.dYtE, S.Ht, S.w1c, S.Sw1, w1b_new, w1t_new,
        wBc, wEc, scc);
    g2b_k<<<128, 256, 0, stream>>>(
        S.dHtW, S.dHtE, KTc, S.w0c, S.Sw0, S.w0b, scc);
  }

  // ---- retrieval through final memory (final w1 copy is slot 0) ----
  mgemm128_k<4><<<dim3(Ii / 128, RowsAll / 128), 256, 0, stream>>>(
      S.Qbb, S.w0b, nullptr, S.Hrb, RowsAll, Ii, Dd);
  mgemm128_k<0><<<dim3(Dd / 128, RowsAll / 128), 256, 0, stream>>>(
      S.Hrb, S.w1b, S.Yr, nullptr, RowsAll, Dd, Ii);
  final4_k<<<RowsAll / 4, 256, 0, stream>>>(S.Qb, S.Yr, S.lnc, out);
}